// Round 15
// baseline (163.225 us; speedup 1.0000x reference)
//
#include <hip/hip_runtime.h>
#include <hip/hip_bf16.h>
#include <math.h>

#define B_N 8
#define S_N 2048
#define C_N 384
#define D_N 64
#define NCHUNK 16         // i-chunks for col_part (128 rows each)
#define NEG_BIG (-1e30f)

typedef __bf16 bf16x8 __attribute__((ext_vector_type(8)));
typedef float f32x4 __attribute__((ext_vector_type(4)));

static __device__ __forceinline__ bf16x8 ldfrag(const __bf16* p) {
  return *reinterpret_cast<const bf16x8*>(p);
}

// ---------------------------------------------------------------------------
// Kernel 0: weight prep. Wt[m][d][c] = (bf16) W_m[c][d].
// ---------------------------------------------------------------------------
__global__ __launch_bounds__(256) void w_prep(
    const float* __restrict__ Wq, const float* __restrict__ Wk,
    const float* __restrict__ Wv, __bf16* __restrict__ Wt) {
  const int idx = blockIdx.x * 256 + threadIdx.x;   // [0, 3*64*384)
  const int m = idx / (64 * C_N);
  const int r = idx % (64 * C_N);
  const int d = r / C_N;
  const int c = r % C_N;
  const float* W = (m == 0) ? Wq : (m == 1) ? Wk : Wv;
  Wt[idx] = (__bf16)W[c * 64 + d];
}

// ---------------------------------------------------------------------------
// Kernel 1: QKV projection via MFMA (unchanged).
// ---------------------------------------------------------------------------
__global__ __launch_bounds__(384) void qkv_mfma(
    const float* __restrict__ x, const __bf16* __restrict__ Wt,
    __bf16* __restrict__ Q, __bf16* __restrict__ K, __bf16* __restrict__ Vt) {
  const int t = threadIdx.x;
  const int w = t >> 6, lane = t & 63, lr = lane & 15, lg = lane >> 4;
  const int mat = w >> 1, rh = w & 1;
  const int row0 = blockIdx.x * 32;                 // flat row in [0, B*S)
  const int ri = row0 + rh * 16 + lr;

  __shared__ __bf16 vtile[32][66];                  // V block, padded

  const float scl = (mat == 0) ? 0.125f : 1.0f;
  const float* xr = x + (size_t)ri * C_N;
  const __bf16* Wm = Wt + (size_t)mat * 64 * C_N;

  f32x4 acc[4];
#pragma unroll
  for (int nt = 0; nt < 4; ++nt) acc[nt] = {0.f, 0.f, 0.f, 0.f};

#pragma unroll 4
  for (int kk = 0; kk < C_N / 32; ++kk) {
    const float4 xa = *reinterpret_cast<const float4*>(xr + kk * 32 + lg * 8);
    const float4 xb = *reinterpret_cast<const float4*>(xr + kk * 32 + lg * 8 + 4);
    bf16x8 a;
    a[0] = (__bf16)(xa.x * scl); a[1] = (__bf16)(xa.y * scl);
    a[2] = (__bf16)(xa.z * scl); a[3] = (__bf16)(xa.w * scl);
    a[4] = (__bf16)(xb.x * scl); a[5] = (__bf16)(xb.y * scl);
    a[6] = (__bf16)(xb.z * scl); a[7] = (__bf16)(xb.w * scl);
#pragma unroll
    for (int nt = 0; nt < 4; ++nt) {
      const bf16x8 bw = ldfrag(Wm + (size_t)(nt * 16 + lr) * C_N + kk * 32 + lg * 8);
      acc[nt] = __builtin_amdgcn_mfma_f32_16x16x32_bf16(a, bw, acc[nt], 0, 0, 0);
    }
  }

  if (mat < 2) {
    __bf16* outp = (mat == 0) ? Q : K;
#pragma unroll
    for (int nt = 0; nt < 4; ++nt)
#pragma unroll
      for (int r = 0; r < 4; ++r)
        outp[(size_t)(row0 + rh * 16 + lg * 4 + r) * 64 + nt * 16 + lr] =
            (__bf16)acc[nt][r];
  } else {
#pragma unroll
    for (int nt = 0; nt < 4; ++nt)
#pragma unroll
      for (int r = 0; r < 4; ++r)
        vtile[rh * 16 + lg * 4 + r][nt * 16 + lr] = (__bf16)acc[nt][r];
  }
  __syncthreads();

  const int b = row0 >> 11, s0 = row0 & (S_N - 1);
  for (int idx = t; idx < 64 * 32; idx += 384) {
    const int d = idx >> 5, s2 = idx & 31;
    Vt[((size_t)b * D_N + d) * S_N + s0 + s2] = vtile[s2][d];
  }
}

// ---------------------------------------------------------------------------
// Kernel 2a: partial column denominators (m == 0). Unchanged from R12.
// ---------------------------------------------------------------------------
__global__ __launch_bounds__(256) void col_part(
    const __bf16* __restrict__ Q, const __bf16* __restrict__ K,
    float* __restrict__ zP) {
  const int wg = blockIdx.x;                       // 32*16*8 = 4096
  const int b  = wg & 7;
  const int jb = (wg >> 3) & 31;
  const int ic = wg >> 8;                          // 0..15
  const int j0 = jb * 64;
  const int t = threadIdx.x;
  const int iStart = max(j0, ic * (S_N / NCHUNK));
  const int iEnd = min(S_N, (ic + 1) * (S_N / NCHUNK));
  const size_t pbase = ((size_t)(b * 32 + jb) * NCHUNK + ic) * 4 * 64;

  if (iStart >= iEnd) {            // neutral partials (256 slots == 256 threads)
    zP[pbase + t] = 0.f;
    return;
  }

  const int w = t >> 6, lane = t & 63, lr = lane & 15, lg = lane >> 4;
  const __bf16* Qb = Q + (size_t)b * S_N * 64;
  const __bf16* Kb = K + (size_t)b * S_N * 64;

  bf16x8 bk[4][2];
#pragma unroll
  for (int jt = 0; jt < 4; ++jt) {
    bk[jt][0] = ldfrag(Kb + (size_t)(j0 + jt * 16 + lr) * 64 + lg * 8);
    bk[jt][1] = ldfrag(Kb + (size_t)(j0 + jt * 16 + lr) * 64 + 32 + lg * 8);
  }

  float z4[4];
#pragma unroll
  for (int jt = 0; jt < 4; ++jt) z4[jt] = 0.f;

  bf16x8 aq0c = ldfrag(Qb + (size_t)(iStart + w * 16 + lr) * 64 + lg * 8);
  bf16x8 aq1c = ldfrag(Qb + (size_t)(iStart + w * 16 + lr) * 64 + 32 + lg * 8);

  for (int i0 = iStart; i0 < iEnd; i0 += 64) {
    const int riN = ((i0 + 64 < iEnd) ? i0 + 64 : i0) + w * 16 + lr;
    const bf16x8 aq0n = ldfrag(Qb + (size_t)riN * 64 + lg * 8);
    const bf16x8 aq1n = ldfrag(Qb + (size_t)riN * 64 + 32 + lg * 8);

    const int ibase = i0 + w * 16 + lg * 4;       // D-row base for this lane
    const bool diag = (i0 == j0);
#pragma unroll
    for (int jt = 0; jt < 4; ++jt) {
      f32x4 s = {0.f, 0.f, 0.f, 0.f};
      s = __builtin_amdgcn_mfma_f32_16x16x32_bf16(aq0c, bk[jt][0], s, 0, 0, 0);
      s = __builtin_amdgcn_mfma_f32_16x16x32_bf16(aq1c, bk[jt][1], s, 0, 0, 0);
      const int jg = j0 + jt * 16 + lr;           // D col = lane&15
      if (diag) {
#pragma unroll
        for (int r = 0; r < 4; ++r)
          if (ibase + r < jg) s[r] = NEG_BIG;     // expf(-1e30) == 0
      }
      float es = __expf(s[0]) + __expf(s[1]) + __expf(s[2]) + __expf(s[3]);
      es += __shfl_xor(es, 16);
      es += __shfl_xor(es, 32);
      z4[jt] += es;
    }
    aq0c = aq0n;
    aq1c = aq1n;
  }

  if (lg == 0) {                                  // one copy per column
#pragma unroll
    for (int jt = 0; jt < 4; ++jt)
      zP[pbase + w * 64 + jt * 16 + lr] = z4[jt];
  }
}

// ---------------------------------------------------------------------------
// Kernel 2b: sum the NCHUNK*4 partials per column -> 1/Z.
// ---------------------------------------------------------------------------
__global__ __launch_bounds__(256) void col_reduce(
    const float* __restrict__ zP, float* __restrict__ rZ) {
  const int idx = blockIdx.x * 256 + threadIdx.x;  // b*S + j
  const int b = idx >> 11;
  const int j = idx & (S_N - 1);
  const int jb = j >> 6, jr = j & 63;
  const size_t base = (size_t)(b * 32 + jb) * NCHUNK * 4 * 64 + jr;

  float z = 0.f;
#pragma unroll 8
  for (int p = 0; p < NCHUNK * 4; ++p) z += zP[base + (size_t)p * 64];

  rZ[idx] = 1.0f / z;
}

// ---------------------------------------------------------------------------
// Kernel 3: output pass, atomic-free with in-block TLP. Block = (b, ib),
// 1024 threads = 16 waves: wave (s, jq) covers strip s (16 rows) and
// j-tiles jb ≡ jq (mod 4). Worst wave: 8 pipelined strip-iterations.
// Quarter-partials combined via LDS staging (2 barriers), which REUSES the
// dead P_lds memory (union). Output stored exactly once, no memset.
// ---------------------------------------------------------------------------
#define LOADKV(KR, VR, J0V) do { \
  _Pragma("unroll") \
  for (int jt = 0; jt < 4; ++jt) { \
    KR[jt][0] = ldfrag(Kb + (size_t)((J0V) + jt * 16 + lr) * 64 + lg * 8); \
    KR[jt][1] = ldfrag(Kb + (size_t)((J0V) + jt * 16 + lr) * 64 + 32 + lg * 8); \
  } \
  _Pragma("unroll") \
  for (int dt = 0; dt < 4; ++dt) { \
    VR[dt][0] = ldfrag(Vb + (size_t)(dt * 16 + lr) * S_N + (J0V) + lg * 8); \
    VR[dt][1] = ldfrag(Vb + (size_t)(dt * 16 + lr) * S_N + (J0V) + 32 + lg * 8); \
  } \
} while (0)

#define COMPUTE(KR, VR, J0V) do { \
  f32x4 s4[4]; \
  _Pragma("unroll") \
  for (int jt = 0; jt < 4; ++jt) { \
    f32x4 s = {0.f, 0.f, 0.f, 0.f}; \
    s = __builtin_amdgcn_mfma_f32_16x16x32_bf16(aq0, KR[jt][0], s, 0, 0, 0); \
    s = __builtin_amdgcn_mfma_f32_16x16x32_bf16(aq1, KR[jt][1], s, 0, 0, 0); \
    s4[jt] = s; \
  } \
  _Pragma("unroll") \
  for (int jt = 0; jt < 4; ++jt) { \
    const int jg = (J0V) + jt * 16 + lr; \
    const float rz = rZb[jg]; \
    _Pragma("unroll") \
    for (int r = 0; r < 4; ++r) { \
      const float pv = (jg <= ibase + r) ? __expf(s4[jt][r]) * rz : 0.f; \
      Pw[(lg * 4 + r) * 72 + jt * 16 + lr] = (__bf16)pv; \
    } \
  } \
  const bf16x8 ap0 = ldfrag(Pw + lr * 72 + lg * 8); \
  const bf16x8 ap1 = ldfrag(Pw + lr * 72 + 32 + lg * 8); \
  _Pragma("unroll") \
  for (int dt = 0; dt < 4; ++dt) { \
    o[dt] = __builtin_amdgcn_mfma_f32_16x16x32_bf16(ap0, VR[dt][0], o[dt], 0, 0, 0); \
    o[dt] = __builtin_amdgcn_mfma_f32_16x16x32_bf16(ap1, VR[dt][1], o[dt], 0, 0, 0); \
  } \
} while (0)

__global__ __launch_bounds__(1024) void attn_out(
    const __bf16* __restrict__ Q, const __bf16* __restrict__ K,
    const __bf16* __restrict__ Vt, const float* __restrict__ rZ,
    float* __restrict__ out) {
  const int wg = blockIdx.x;                       // 256 blocks
  const int b  = wg & 7;                           // XCD swizzle
  const int ib = wg >> 3;                          // 0..31

  const int t = threadIdx.x;
  const int w = t >> 6;                            // wave 0..15
  const int s = w & 3;                             // strip (16 rows)
  const int jq = w >> 2;                           // j-quarter 0..3
  const int lane = t & 63, lr = lane & 15, lg = lane >> 4;
  const int i0 = ib * 64;

  // union: per-wave P tiles [16][16][72] bf16 (36864 B) while computing;
  // f32 staging [3][4][16][65] (49920 B) for the quarter-reduce afterwards.
  __shared__ __align__(16) unsigned char smem[49920];
  __bf16* Pw = (__bf16*)(smem) + (size_t)w * 16 * 72;

  const __bf16* Qb = Q + (size_t)b * S_N * 64;
  const __bf16* Kb = K + (size_t)b * S_N * 64;
  const __bf16* Vb = Vt + (size_t)b * D_N * S_N;
  const float* rZb = rZ + (size_t)b * S_N;

  const int ri = i0 + s * 16 + lr;
  const bf16x8 aq0 = ldfrag(Qb + (size_t)ri * 64 + lg * 8);
  const bf16x8 aq1 = ldfrag(Qb + (size_t)ri * 64 + 32 + lg * 8);
  const int ibase = i0 + s * 16 + lg * 4;          // D-row base

  f32x4 o[4];
#pragma unroll
  for (int dt = 0; dt < 4; ++dt) o[dt] = {0.f, 0.f, 0.f, 0.f};

  bf16x8 kA[4][2], vA[4][2], kB[4][2], vB[4][2];

  int jb = jq;
  if (jb <= ib) {
    LOADKV(kA, vA, jb * 64);
    while (true) {
      const bool hasB = (jb + 4 <= ib);
      if (hasB) LOADKV(kB, vB, (jb + 4) * 64);     // prefetch under A's chain
      COMPUTE(kA, vA, jb * 64);
      if (!hasB) break;
      const bool hasA2 = (jb + 8 <= ib);
      if (hasA2) LOADKV(kA, vA, (jb + 8) * 64);    // prefetch under B's chain
      COMPUTE(kB, vB, (jb + 4) * 64);
      if (!hasA2) break;
      jb += 8;
    }
  }

  __syncthreads();                                 // all P-region use done

  float* stg = (float*)smem;                       // [3][4][16][65]
  if (jq > 0) {
#pragma unroll
    for (int dt = 0; dt < 4; ++dt)
#pragma unroll
      for (int r = 0; r < 4; ++r)
        stg[(size_t)(jq - 1) * 4160 + (s * 16 + lg * 4 + r) * 65 + dt * 16 + lr] =
            o[dt][r];
  }
  __syncthreads();                                 // staging visible

  if (jq == 0) {
#pragma unroll
    for (int q = 0; q < 3; ++q)
#pragma unroll
      for (int dt = 0; dt < 4; ++dt)
#pragma unroll
        for (int r = 0; r < 4; ++r)
          o[dt][r] += stg[(size_t)q * 4160 + (s * 16 + lg * 4 + r) * 65 + dt * 16 + lr];

    float* ob = out + (size_t)b * S_N * D_N;
#pragma unroll
    for (int dt = 0; dt < 4; ++dt)
#pragma unroll
      for (int r = 0; r < 4; ++r)
        ob[(size_t)(ibase + r) * D_N + dt * 16 + lr] = o[dt][r];
  }
}

extern "C" void kernel_launch(void* const* d_in, const int* in_sizes, int n_in,
                              void* d_out, int out_size, void* d_ws, size_t ws_size,
                              hipStream_t stream) {
  (void)in_sizes; (void)n_in; (void)ws_size; (void)out_size;
  const float* x  = (const float*)d_in[0];
  const float* Wq = (const float*)d_in[1];
  const float* Wk = (const float*)d_in[2];
  const float* Wv = (const float*)d_in[3];
  float* out = (float*)d_out;

  __bf16* Qb = (__bf16*)d_ws;                         // [B*S][64] pre-scaled
  __bf16* Kb = Qb + (size_t)B_N * S_N * D_N;          // [B*S][64]
  __bf16* Vt = Kb + (size_t)B_N * S_N * D_N;          // [B][64][S] transposed
  float* rZ = (float*)(Vt + (size_t)B_N * S_N * D_N); // [B,S]
  float* zP = rZ + (size_t)B_N * S_N;                 // [B,32,NCHUNK,4,64]
  __bf16* Wt = (__bf16*)(zP + (size_t)B_N * 32 * NCHUNK * 4 * 64); // [3][64][384]

  w_prep<<<dim3(3 * 64 * C_N / 256), dim3(256), 0, stream>>>(Wq, Wk, Wv, Wt);
  qkv_mfma<<<dim3(B_N * S_N / 32), dim3(384), 0, stream>>>(x, Wt, Qb, Kb, Vt);
  col_part<<<dim3(32 * NCHUNK * B_N), dim3(256), 0, stream>>>(Qb, Kb, zP);
  col_reduce<<<dim3(B_N * S_N / 256), dim3(256), 0, stream>>>(zP, rZ);
  attn_out<<<dim3(32 * B_N), dim3(1024), 0, stream>>>(Qb, Kb, Vt, rZ, out);
}

// Round 16
// 118.730 us; speedup vs baseline: 1.3748x; 1.3748x over previous
//
#include <hip/hip_runtime.h>
#include <hip/hip_bf16.h>
#include <math.h>

#define B_N 8
#define S_N 2048
#define C_N 384
#define D_N 64
#define NCHUNK 16         // i-chunks for col_part (128 rows each)
#define NEG_BIG (-1e30f)

typedef __bf16 bf16x8 __attribute__((ext_vector_type(8)));
typedef float f32x4 __attribute__((ext_vector_type(4)));

static __device__ __forceinline__ bf16x8 ldfrag(const __bf16* p) {
  return *reinterpret_cast<const bf16x8*>(p);
}

// ---------------------------------------------------------------------------
// Kernel 0: weight prep. Wt[m][d][c] = (bf16) W_m[c][d].
// ---------------------------------------------------------------------------
__global__ __launch_bounds__(256) void w_prep(
    const float* __restrict__ Wq, const float* __restrict__ Wk,
    const float* __restrict__ Wv, __bf16* __restrict__ Wt) {
  const int idx = blockIdx.x * 256 + threadIdx.x;   // [0, 3*64*384)
  const int m = idx / (64 * C_N);
  const int r = idx % (64 * C_N);
  const int d = r / C_N;
  const int c = r % C_N;
  const float* W = (m == 0) ? Wq : (m == 1) ? Wk : Wv;
  Wt[idx] = (__bf16)W[c * 64 + d];
}

// ---------------------------------------------------------------------------
// Kernel 1: QKV projection via MFMA (unchanged).
// ---------------------------------------------------------------------------
__global__ __launch_bounds__(384) void qkv_mfma(
    const float* __restrict__ x, const __bf16* __restrict__ Wt,
    __bf16* __restrict__ Q, __bf16* __restrict__ K, __bf16* __restrict__ Vt) {
  const int t = threadIdx.x;
  const int w = t >> 6, lane = t & 63, lr = lane & 15, lg = lane >> 4;
  const int mat = w >> 1, rh = w & 1;
  const int row0 = blockIdx.x * 32;                 // flat row in [0, B*S)
  const int ri = row0 + rh * 16 + lr;

  __shared__ __bf16 vtile[32][66];                  // V block, padded

  const float scl = (mat == 0) ? 0.125f : 1.0f;
  const float* xr = x + (size_t)ri * C_N;
  const __bf16* Wm = Wt + (size_t)mat * 64 * C_N;

  f32x4 acc[4];
#pragma unroll
  for (int nt = 0; nt < 4; ++nt) acc[nt] = {0.f, 0.f, 0.f, 0.f};

#pragma unroll 4
  for (int kk = 0; kk < C_N / 32; ++kk) {
    const float4 xa = *reinterpret_cast<const float4*>(xr + kk * 32 + lg * 8);
    const float4 xb = *reinterpret_cast<const float4*>(xr + kk * 32 + lg * 8 + 4);
    bf16x8 a;
    a[0] = (__bf16)(xa.x * scl); a[1] = (__bf16)(xa.y * scl);
    a[2] = (__bf16)(xa.z * scl); a[3] = (__bf16)(xa.w * scl);
    a[4] = (__bf16)(xb.x * scl); a[5] = (__bf16)(xb.y * scl);
    a[6] = (__bf16)(xb.z * scl); a[7] = (__bf16)(xb.w * scl);
#pragma unroll
    for (int nt = 0; nt < 4; ++nt) {
      const bf16x8 bw = ldfrag(Wm + (size_t)(nt * 16 + lr) * C_N + kk * 32 + lg * 8);
      acc[nt] = __builtin_amdgcn_mfma_f32_16x16x32_bf16(a, bw, acc[nt], 0, 0, 0);
    }
  }

  if (mat < 2) {
    __bf16* outp = (mat == 0) ? Q : K;
#pragma unroll
    for (int nt = 0; nt < 4; ++nt)
#pragma unroll
      for (int r = 0; r < 4; ++r)
        outp[(size_t)(row0 + rh * 16 + lg * 4 + r) * 64 + nt * 16 + lr] =
            (__bf16)acc[nt][r];
  } else {
#pragma unroll
    for (int nt = 0; nt < 4; ++nt)
#pragma unroll
      for (int r = 0; r < 4; ++r)
        vtile[rh * 16 + lg * 4 + r][nt * 16 + lr] = (__bf16)acc[nt][r];
  }
  __syncthreads();

  const int b = row0 >> 11, s0 = row0 & (S_N - 1);
  for (int idx = t; idx < 64 * 32; idx += 384) {
    const int d = idx >> 5, s2 = idx & 31;
    Vt[((size_t)b * D_N + d) * S_N + s0 + s2] = vtile[s2][d];
  }
}

// ---------------------------------------------------------------------------
// Kernel 2a: partial column denominators (m == 0). Unchanged from R12.
// ---------------------------------------------------------------------------
__global__ __launch_bounds__(256) void col_part(
    const __bf16* __restrict__ Q, const __bf16* __restrict__ K,
    float* __restrict__ zP) {
  const int wg = blockIdx.x;                       // 32*16*8 = 4096
  const int b  = wg & 7;
  const int jb = (wg >> 3) & 31;
  const int ic = wg >> 8;                          // 0..15
  const int j0 = jb * 64;
  const int t = threadIdx.x;
  const int iStart = max(j0, ic * (S_N / NCHUNK));
  const int iEnd = min(S_N, (ic + 1) * (S_N / NCHUNK));
  const size_t pbase = ((size_t)(b * 32 + jb) * NCHUNK + ic) * 4 * 64;

  if (iStart >= iEnd) {            // neutral partials (256 slots == 256 threads)
    zP[pbase + t] = 0.f;
    return;
  }

  const int w = t >> 6, lane = t & 63, lr = lane & 15, lg = lane >> 4;
  const __bf16* Qb = Q + (size_t)b * S_N * 64;
  const __bf16* Kb = K + (size_t)b * S_N * 64;

  bf16x8 bk[4][2];
#pragma unroll
  for (int jt = 0; jt < 4; ++jt) {
    bk[jt][0] = ldfrag(Kb + (size_t)(j0 + jt * 16 + lr) * 64 + lg * 8);
    bk[jt][1] = ldfrag(Kb + (size_t)(j0 + jt * 16 + lr) * 64 + 32 + lg * 8);
  }

  float z4[4];
#pragma unroll
  for (int jt = 0; jt < 4; ++jt) z4[jt] = 0.f;

  bf16x8 aq0c = ldfrag(Qb + (size_t)(iStart + w * 16 + lr) * 64 + lg * 8);
  bf16x8 aq1c = ldfrag(Qb + (size_t)(iStart + w * 16 + lr) * 64 + 32 + lg * 8);

  for (int i0 = iStart; i0 < iEnd; i0 += 64) {
    const int riN = ((i0 + 64 < iEnd) ? i0 + 64 : i0) + w * 16 + lr;
    const bf16x8 aq0n = ldfrag(Qb + (size_t)riN * 64 + lg * 8);
    const bf16x8 aq1n = ldfrag(Qb + (size_t)riN * 64 + 32 + lg * 8);

    const int ibase = i0 + w * 16 + lg * 4;       // D-row base for this lane
    const bool diag = (i0 == j0);
#pragma unroll
    for (int jt = 0; jt < 4; ++jt) {
      f32x4 s = {0.f, 0.f, 0.f, 0.f};
      s = __builtin_amdgcn_mfma_f32_16x16x32_bf16(aq0c, bk[jt][0], s, 0, 0, 0);
      s = __builtin_amdgcn_mfma_f32_16x16x32_bf16(aq1c, bk[jt][1], s, 0, 0, 0);
      const int jg = j0 + jt * 16 + lr;           // D col = lane&15
      if (diag) {
#pragma unroll
        for (int r = 0; r < 4; ++r)
          if (ibase + r < jg) s[r] = NEG_BIG;     // expf(-1e30) == 0
      }
      float es = __expf(s[0]) + __expf(s[1]) + __expf(s[2]) + __expf(s[3]);
      es += __shfl_xor(es, 16);
      es += __shfl_xor(es, 32);
      z4[jt] += es;
    }
    aq0c = aq0n;
    aq1c = aq1n;
  }

  if (lg == 0) {                                  // one copy per column
#pragma unroll
    for (int jt = 0; jt < 4; ++jt)
      zP[pbase + w * 64 + jt * 16 + lr] = z4[jt];
  }
}

// ---------------------------------------------------------------------------
// Kernel 2b: sum the NCHUNK*4 partials per column -> 1/Z.
// ---------------------------------------------------------------------------
__global__ __launch_bounds__(256) void col_reduce(
    const float* __restrict__ zP, float* __restrict__ rZ) {
  const int idx = blockIdx.x * 256 + threadIdx.x;  // b*S + j
  const int b = idx >> 11;
  const int j = idx & (S_N - 1);
  const int jb = j >> 6, jr = j & 63;
  const size_t base = (size_t)(b * 32 + jb) * NCHUNK * 4 * 64 + jr;

  float z = 0.f;
#pragma unroll 8
  for (int p = 0; p < NCHUNK * 4; ++p) z += zP[base + (size_t)p * 64];

  rZ[idx] = 1.0f / z;
}

// ---------------------------------------------------------------------------
// Kernel 3: output pass, atomic-free + in-block TLP, SINGLE-BANK registers.
// Block = (b, ib), 1024 threads = 16 waves: wave (s, jq) covers strip s and
// j-tiles jb ≡ jq (mod 4). No register double-buffer (R15 spilled at 128+
// VGPRs of banks); 4 waves/SIMD of TLP hides the per-iteration load stalls.
// V fragments are loaded at their use point (R6/R11 body: VGPR 32-52).
// Quarter-partials combined via LDS staging reusing the dead P region.
// ---------------------------------------------------------------------------
__global__ __launch_bounds__(1024) void attn_out(
    const __bf16* __restrict__ Q, const __bf16* __restrict__ K,
    const __bf16* __restrict__ Vt, const float* __restrict__ rZ,
    float* __restrict__ out) {
  const int wg = blockIdx.x;                       // 256 blocks
  const int b  = wg & 7;                           // XCD swizzle
  const int ib = wg >> 3;                          // 0..31

  const int t = threadIdx.x;
  const int w = t >> 6;                            // wave 0..15
  const int s = w & 3;                             // strip (16 rows)
  const int jq = w >> 2;                           // j-quarter 0..3
  const int lane = t & 63, lr = lane & 15, lg = lane >> 4;
  const int i0 = ib * 64;

  // union: per-wave P tiles [16][16][72] bf16 (36864 B) while computing;
  // f32 staging [3][4][16][65] (49920 B) for the quarter-reduce afterwards.
  __shared__ __align__(16) unsigned char smem[49920];
  __bf16* Pw = (__bf16*)(smem) + (size_t)w * 16 * 72;

  const __bf16* Qb = Q + (size_t)b * S_N * 64;
  const __bf16* Kb = K + (size_t)b * S_N * 64;
  const __bf16* Vb = Vt + (size_t)b * D_N * S_N;
  const float* rZb = rZ + (size_t)b * S_N;

  const int ri = i0 + s * 16 + lr;
  const bf16x8 aq0 = ldfrag(Qb + (size_t)ri * 64 + lg * 8);
  const bf16x8 aq1 = ldfrag(Qb + (size_t)ri * 64 + 32 + lg * 8);
  const int ibase = i0 + s * 16 + lg * 4;          // D-row base

  f32x4 o[4];
#pragma unroll
  for (int dt = 0; dt < 4; ++dt) o[dt] = {0.f, 0.f, 0.f, 0.f};

  for (int jb = jq; jb <= ib; jb += 4) {
    const int j0 = jb * 64;

    // ---- K fragments + scores ----
    f32x4 s4[4];
#pragma unroll
    for (int jt = 0; jt < 4; ++jt) {
      const bf16x8 k0 = ldfrag(Kb + (size_t)(j0 + jt * 16 + lr) * 64 + lg * 8);
      const bf16x8 k1 = ldfrag(Kb + (size_t)(j0 + jt * 16 + lr) * 64 + 32 + lg * 8);
      f32x4 sx = {0.f, 0.f, 0.f, 0.f};
      sx = __builtin_amdgcn_mfma_f32_16x16x32_bf16(aq0, k0, sx, 0, 0, 0);
      sx = __builtin_amdgcn_mfma_f32_16x16x32_bf16(aq1, k1, sx, 0, 0, 0);
      s4[jt] = sx;
    }

    // ---- P = exp(s) * rZ (m == 0; causal mask folded in) ----
#pragma unroll
    for (int jt = 0; jt < 4; ++jt) {
      const int jg = j0 + jt * 16 + lr;            // D col
      const float rz = rZb[jg];
#pragma unroll
      for (int r = 0; r < 4; ++r) {
        const float pv = (jg <= ibase + r) ? __expf(s4[jt][r]) * rz : 0.f;
        Pw[(lg * 4 + r) * 72 + jt * 16 + lr] = (__bf16)pv;
      }
    }

    // ---- PV: A = P via per-wave LDS transpose; V at use point ----
    const bf16x8 ap0 = ldfrag(Pw + lr * 72 + lg * 8);
    const bf16x8 ap1 = ldfrag(Pw + lr * 72 + 32 + lg * 8);
#pragma unroll
    for (int dt = 0; dt < 4; ++dt) {
      const bf16x8 bv0 = ldfrag(Vb + (size_t)(dt * 16 + lr) * S_N + j0 + lg * 8);
      const bf16x8 bv1 = ldfrag(Vb + (size_t)(dt * 16 + lr) * S_N + j0 + 32 + lg * 8);
      o[dt] = __builtin_amdgcn_mfma_f32_16x16x32_bf16(ap0, bv0, o[dt], 0, 0, 0);
      o[dt] = __builtin_amdgcn_mfma_f32_16x16x32_bf16(ap1, bv1, o[dt], 0, 0, 0);
    }
  }

  __syncthreads();                                 // all P-region use done

  float* stg = (float*)smem;                       // [3][4][16][65]
  if (jq > 0) {
#pragma unroll
    for (int dt = 0; dt < 4; ++dt)
#pragma unroll
      for (int r = 0; r < 4; ++r)
        stg[(size_t)(jq - 1) * 4160 + (s * 16 + lg * 4 + r) * 65 + dt * 16 + lr] =
            o[dt][r];
  }
  __syncthreads();                                 // staging visible

  if (jq == 0) {
#pragma unroll
    for (int q = 0; q < 3; ++q)
#pragma unroll
      for (int dt = 0; dt < 4; ++dt)
#pragma unroll
        for (int r = 0; r < 4; ++r)
          o[dt][r] += stg[(size_t)q * 4160 + (s * 16 + lg * 4 + r) * 65 + dt * 16 + lr];

    float* ob = out + (size_t)b * S_N * D_N;
#pragma unroll
    for (int dt = 0; dt < 4; ++dt)
#pragma unroll
      for (int r = 0; r < 4; ++r)
        ob[(size_t)(ibase + r) * D_N + dt * 16 + lr] = o[dt][r];
  }
}

extern "C" void kernel_launch(void* const* d_in, const int* in_sizes, int n_in,
                              void* d_out, int out_size, void* d_ws, size_t ws_size,
                              hipStream_t stream) {
  (void)in_sizes; (void)n_in; (void)ws_size; (void)out_size;
  const float* x  = (const float*)d_in[0];
  const float* Wq = (const float*)d_in[1];
  const float* Wk = (const float*)d_in[2];
  const float* Wv = (const float*)d_in[3];
  float* out = (float*)d_out;

  __bf16* Qb = (__bf16*)d_ws;                         // [B*S][64] pre-scaled
  __bf16* Kb = Qb + (size_t)B_N * S_N * D_N;          // [B*S][64]
  __bf16* Vt = Kb + (size_t)B_N * S_N * D_N;          // [B][64][S] transposed
  float* rZ = (float*)(Vt + (size_t)B_N * S_N * D_N); // [B,S]
  float* zP = rZ + (size_t)B_N * S_N;                 // [B,32,NCHUNK,4,64]
  __bf16* Wt = (__bf16*)(zP + (size_t)B_N * 32 * NCHUNK * 4 * 64); // [3][64][384]

  w_prep<<<dim3(3 * 64 * C_N / 256), dim3(256), 0, stream>>>(Wq, Wk, Wv, Wt);
  qkv_mfma<<<dim3(B_N * S_N / 32), dim3(384), 0, stream>>>(x, Wt, Qb, Kb, Vt);
  col_part<<<dim3(32 * NCHUNK * B_N), dim3(256), 0, stream>>>(Qb, Kb, zP);
  col_reduce<<<dim3(B_N * S_N / 256), dim3(256), 0, stream>>>(zP, rZ);
  attn_out<<<dim3(32 * B_N), dim3(1024), 0, stream>>>(Qb, Kb, Vt, rZ, out);
}

// Round 17
// 90.720 us; speedup vs baseline: 1.7992x; 1.3087x over previous
//
#include <hip/hip_runtime.h>
#include <hip/hip_bf16.h>
#include <math.h>

#define B_N 8
#define S_N 2048
#define C_N 384
#define D_N 64
#define NCHUNK 16         // i-chunks for col_part (128 rows each)
#define NEG_BIG (-1e30f)

typedef __bf16 bf16x8 __attribute__((ext_vector_type(8)));
typedef float f32x4 __attribute__((ext_vector_type(4)));

static __device__ __forceinline__ bf16x8 ldfrag(const __bf16* p) {
  return *reinterpret_cast<const bf16x8*>(p);
}

// async 16B global -> LDS (linear dest, per-lane global src)
static __device__ __forceinline__ void gload16(void* lds, const void* gsrc) {
  __builtin_amdgcn_global_load_lds(
      (const __attribute__((address_space(1))) unsigned int*)gsrc,
      (__attribute__((address_space(3))) unsigned int*)lds, 16, 0, 0);
}

// ---------------------------------------------------------------------------
// Kernel 0: weight prep. Wt[m][d][c] = (bf16) W_m[c][d].
// ---------------------------------------------------------------------------
__global__ __launch_bounds__(256) void w_prep(
    const float* __restrict__ Wq, const float* __restrict__ Wk,
    const float* __restrict__ Wv, __bf16* __restrict__ Wt) {
  const int idx = blockIdx.x * 256 + threadIdx.x;   // [0, 3*64*384)
  const int m = idx / (64 * C_N);
  const int r = idx % (64 * C_N);
  const int d = r / C_N;
  const int c = r % C_N;
  const float* W = (m == 0) ? Wq : (m == 1) ? Wk : Wv;
  Wt[idx] = (__bf16)W[c * 64 + d];
}

// ---------------------------------------------------------------------------
// Kernel 1: QKV projection via MFMA (unchanged).
// ---------------------------------------------------------------------------
__global__ __launch_bounds__(384) void qkv_mfma(
    const float* __restrict__ x, const __bf16* __restrict__ Wt,
    __bf16* __restrict__ Q, __bf16* __restrict__ K, __bf16* __restrict__ Vt) {
  const int t = threadIdx.x;
  const int w = t >> 6, lane = t & 63, lr = lane & 15, lg = lane >> 4;
  const int mat = w >> 1, rh = w & 1;
  const int row0 = blockIdx.x * 32;                 // flat row in [0, B*S)
  const int ri = row0 + rh * 16 + lr;

  __shared__ __bf16 vtile[32][66];                  // V block, padded

  const float scl = (mat == 0) ? 0.125f : 1.0f;
  const float* xr = x + (size_t)ri * C_N;
  const __bf16* Wm = Wt + (size_t)mat * 64 * C_N;

  f32x4 acc[4];
#pragma unroll
  for (int nt = 0; nt < 4; ++nt) acc[nt] = {0.f, 0.f, 0.f, 0.f};

#pragma unroll 4
  for (int kk = 0; kk < C_N / 32; ++kk) {
    const float4 xa = *reinterpret_cast<const float4*>(xr + kk * 32 + lg * 8);
    const float4 xb = *reinterpret_cast<const float4*>(xr + kk * 32 + lg * 8 + 4);
    bf16x8 a;
    a[0] = (__bf16)(xa.x * scl); a[1] = (__bf16)(xa.y * scl);
    a[2] = (__bf16)(xa.z * scl); a[3] = (__bf16)(xa.w * scl);
    a[4] = (__bf16)(xb.x * scl); a[5] = (__bf16)(xb.y * scl);
    a[6] = (__bf16)(xb.z * scl); a[7] = (__bf16)(xb.w * scl);
#pragma unroll
    for (int nt = 0; nt < 4; ++nt) {
      const bf16x8 bw = ldfrag(Wm + (size_t)(nt * 16 + lr) * C_N + kk * 32 + lg * 8);
      acc[nt] = __builtin_amdgcn_mfma_f32_16x16x32_bf16(a, bw, acc[nt], 0, 0, 0);
    }
  }

  if (mat < 2) {
    __bf16* outp = (mat == 0) ? Q : K;
#pragma unroll
    for (int nt = 0; nt < 4; ++nt)
#pragma unroll
      for (int r = 0; r < 4; ++r)
        outp[(size_t)(row0 + rh * 16 + lg * 4 + r) * 64 + nt * 16 + lr] =
            (__bf16)acc[nt][r];
  } else {
#pragma unroll
    for (int nt = 0; nt < 4; ++nt)
#pragma unroll
      for (int r = 0; r < 4; ++r)
        vtile[rh * 16 + lg * 4 + r][nt * 16 + lr] = (__bf16)acc[nt][r];
  }
  __syncthreads();

  const int b = row0 >> 11, s0 = row0 & (S_N - 1);
  for (int idx = t; idx < 64 * 32; idx += 384) {
    const int d = idx >> 5, s2 = idx & 31;
    Vt[((size_t)b * D_N + d) * S_N + s0 + s2] = vtile[s2][d];
  }
}

// ---------------------------------------------------------------------------
// Kernel 2a: partial column denominators (m == 0). Unchanged from R12.
// ---------------------------------------------------------------------------
__global__ __launch_bounds__(256) void col_part(
    const __bf16* __restrict__ Q, const __bf16* __restrict__ K,
    float* __restrict__ zP) {
  const int wg = blockIdx.x;                       // 32*16*8 = 4096
  const int b  = wg & 7;
  const int jb = (wg >> 3) & 31;
  const int ic = wg >> 8;                          // 0..15
  const int j0 = jb * 64;
  const int t = threadIdx.x;
  const int iStart = max(j0, ic * (S_N / NCHUNK));
  const int iEnd = min(S_N, (ic + 1) * (S_N / NCHUNK));
  const size_t pbase = ((size_t)(b * 32 + jb) * NCHUNK + ic) * 4 * 64;

  if (iStart >= iEnd) {            // neutral partials (256 slots == 256 threads)
    zP[pbase + t] = 0.f;
    return;
  }

  const int w = t >> 6, lane = t & 63, lr = lane & 15, lg = lane >> 4;
  const __bf16* Qb = Q + (size_t)b * S_N * 64;
  const __bf16* Kb = K + (size_t)b * S_N * 64;

  bf16x8 bk[4][2];
#pragma unroll
  for (int jt = 0; jt < 4; ++jt) {
    bk[jt][0] = ldfrag(Kb + (size_t)(j0 + jt * 16 + lr) * 64 + lg * 8);
    bk[jt][1] = ldfrag(Kb + (size_t)(j0 + jt * 16 + lr) * 64 + 32 + lg * 8);
  }

  float z4[4];
#pragma unroll
  for (int jt = 0; jt < 4; ++jt) z4[jt] = 0.f;

  bf16x8 aq0c = ldfrag(Qb + (size_t)(iStart + w * 16 + lr) * 64 + lg * 8);
  bf16x8 aq1c = ldfrag(Qb + (size_t)(iStart + w * 16 + lr) * 64 + 32 + lg * 8);

  for (int i0 = iStart; i0 < iEnd; i0 += 64) {
    const int riN = ((i0 + 64 < iEnd) ? i0 + 64 : i0) + w * 16 + lr;
    const bf16x8 aq0n = ldfrag(Qb + (size_t)riN * 64 + lg * 8);
    const bf16x8 aq1n = ldfrag(Qb + (size_t)riN * 64 + 32 + lg * 8);

    const int ibase = i0 + w * 16 + lg * 4;       // D-row base for this lane
    const bool diag = (i0 == j0);
#pragma unroll
    for (int jt = 0; jt < 4; ++jt) {
      f32x4 s = {0.f, 0.f, 0.f, 0.f};
      s = __builtin_amdgcn_mfma_f32_16x16x32_bf16(aq0c, bk[jt][0], s, 0, 0, 0);
      s = __builtin_amdgcn_mfma_f32_16x16x32_bf16(aq1c, bk[jt][1], s, 0, 0, 0);
      const int jg = j0 + jt * 16 + lr;           // D col = lane&15
      if (diag) {
#pragma unroll
        for (int r = 0; r < 4; ++r)
          if (ibase + r < jg) s[r] = NEG_BIG;     // expf(-1e30) == 0
      }
      float es = __expf(s[0]) + __expf(s[1]) + __expf(s[2]) + __expf(s[3]);
      es += __shfl_xor(es, 16);
      es += __shfl_xor(es, 32);
      z4[jt] += es;
    }
    aq0c = aq0n;
    aq1c = aq1n;
  }

  if (lg == 0) {                                  // one copy per column
#pragma unroll
    for (int jt = 0; jt < 4; ++jt)
      zP[pbase + w * 64 + jt * 16 + lr] = z4[jt];
  }
}

// ---------------------------------------------------------------------------
// Kernel 2b: sum the NCHUNK*4 partials per column -> 1/Z.
// ---------------------------------------------------------------------------
__global__ __launch_bounds__(256) void col_reduce(
    const float* __restrict__ zP, float* __restrict__ rZ) {
  const int idx = blockIdx.x * 256 + threadIdx.x;  // b*S + j
  const int b = idx >> 11;
  const int j = idx & (S_N - 1);
  const int jb = j >> 6, jr = j & 63;
  const size_t base = (size_t)(b * 32 + jb) * NCHUNK * 4 * 64 + jr;

  float z = 0.f;
#pragma unroll 8
  for (int p = 0; p < NCHUNK * 4; ++p) z += zP[base + (size_t)p * 64];

  rZ[idx] = 1.0f / z;
}

// ---------------------------------------------------------------------------
// Kernel 3: output pass, flash-style LDS staging. Block = (b, ib), 16 waves.
// Per jb tile: waves 0-7 DMA K-tile, 8-15 DMA V-tile via global_load_lds
// (double-buffered; source pre-swizzled chunk^=(row&7) so the swizzled
// ds_read is 2-way-max bank aliased). Wave (s,q): QK for (strip s, j-tile q),
// then PV for (strip s, d-quarter q) -> each wave owns a distinct 16x16
// output tile. No atomics, no reduce, ~40 VGPR live set.
// ---------------------------------------------------------------------------
__global__ __launch_bounds__(1024) void attn_out(
    const __bf16* __restrict__ Q, const __bf16* __restrict__ K,
    const __bf16* __restrict__ Vt, const float* __restrict__ rZ,
    float* __restrict__ out) {
  const int wg = blockIdx.x;                       // 256 blocks
  const int b  = wg & 7;                           // XCD swizzle
  const int ib = wg >> 3;                          // 0..31

  const int t = threadIdx.x;
  const int w = t >> 6;                            // wave 0..15
  const int s = w & 3;                             // strip (16 rows)
  const int q = w >> 2;                            // j-tile (QK) / d-quarter (PV)
  const int lane = t & 63, lr = lane & 15, lg = lane >> 4;
  const int i0 = ib * 64;

  __shared__ __align__(16) __bf16 KT[2][64][64];   // source-swizzled rows
  __shared__ __align__(16) __bf16 VT[2][64][64];   // source-swizzled rows
  __shared__ __align__(16) __bf16 P[4][16][72];    // P tiles, padded

  const __bf16* Qb  = Q  + (size_t)b * S_N * 64;
  const __bf16* Kb  = K  + (size_t)b * S_N * 64;
  const __bf16* Vtb = Vt + (size_t)b * D_N * S_N;
  const float*  rZb = rZ + (size_t)b * S_N;

  // staging role: waves 0-7 -> K rows, waves 8-15 -> V rows
  const int str  = t & 511;
  const int srow = str >> 3;                       // 0..63
  const int schk = str & 7;                        // 16B chunk within row
  const int gchk = schk ^ (srow & 7);              // inverse-swizzled source
  const bool isK = (t < 512);

  // Q fragments (registers, live whole kernel)
  const int ri = i0 + s * 16 + lr;
  const bf16x8 aq0 = ldfrag(Qb + (size_t)ri * 64 + lg * 8);
  const bf16x8 aq1 = ldfrag(Qb + (size_t)ri * 64 + 32 + lg * 8);
  const int ibase = i0 + s * 16 + lg * 4;          // D-row base

  f32x4 o = {0.f, 0.f, 0.f, 0.f};

  // prologue: stage tile jb=0 into buffer 0
  if (isK) gload16(&KT[0][srow][schk * 8], Kb + (size_t)srow * 64 + gchk * 8);
  else     gload16(&VT[0][srow][schk * 8], Vtb + (size_t)srow * S_N + gchk * 8);
  __syncthreads();

  int cur = 0;
  for (int jb = 0; jb <= ib; ++jb) {
    const int j0 = jb * 64;
    // ---- fire next tile's DMA (drains at the next barrier) ----
    if (jb + 1 <= ib) {
      const int j0n = j0 + 64;
      if (isK) gload16(&KT[cur ^ 1][srow][schk * 8],
                       Kb + (size_t)(j0n + srow) * 64 + gchk * 8);
      else     gload16(&VT[cur ^ 1][srow][schk * 8],
                       Vtb + (size_t)srow * S_N + j0n + gchk * 8);
    }

    // ---- QK: wave (s,q) computes strip s x j-tile q ----
    const int krow = q * 16 + lr;
    const bf16x8 bk0 = ldfrag(&KT[cur][krow][(lg ^ (krow & 7)) * 8]);
    const bf16x8 bk1 = ldfrag(&KT[cur][krow][((4 + lg) ^ (krow & 7)) * 8]);
    f32x4 s4 = {0.f, 0.f, 0.f, 0.f};
    s4 = __builtin_amdgcn_mfma_f32_16x16x32_bf16(aq0, bk0, s4, 0, 0, 0);
    s4 = __builtin_amdgcn_mfma_f32_16x16x32_bf16(aq1, bk1, s4, 0, 0, 0);

    const int jg = j0 + q * 16 + lr;               // D col
    const float rz = rZb[jg];
#pragma unroll
    for (int r = 0; r < 4; ++r) {
      const float pv = (jg <= ibase + r) ? __expf(s4[r]) * rz : 0.f;
      P[s][lg * 4 + r][q * 16 + lr] = (__bf16)pv;
    }
    __syncthreads();   // P visible; next tile's DMA drained

    // ---- PV: wave (s,q) accumulates strip s x d-quarter q ----
    const bf16x8 ap0 = ldfrag(&P[s][lr][lg * 8]);
    const bf16x8 ap1 = ldfrag(&P[s][lr][32 + lg * 8]);
    const int vrow = q * 16 + lr;
    const bf16x8 bv0 = ldfrag(&VT[cur][vrow][(lg ^ (vrow & 7)) * 8]);
    const bf16x8 bv1 = ldfrag(&VT[cur][vrow][((4 + lg) ^ (vrow & 7)) * 8]);
    o = __builtin_amdgcn_mfma_f32_16x16x32_bf16(ap0, bv0, o, 0, 0, 0);
    o = __builtin_amdgcn_mfma_f32_16x16x32_bf16(ap1, bv1, o, 0, 0, 0);
    __syncthreads();   // all reads of tile[cur] and P done
    cur ^= 1;
  }

  float* ob = out + (size_t)b * S_N * D_N;
#pragma unroll
  for (int r = 0; r < 4; ++r)
    ob[(size_t)(i0 + s * 16 + lg * 4 + r) * 64 + q * 16 + lr] = o[r];
}

extern "C" void kernel_launch(void* const* d_in, const int* in_sizes, int n_in,
                              void* d_out, int out_size, void* d_ws, size_t ws_size,
                              hipStream_t stream) {
  (void)in_sizes; (void)n_in; (void)ws_size; (void)out_size;
  const float* x  = (const float*)d_in[0];
  const float* Wq = (const float*)d_in[1];
  const float* Wk = (const float*)d_in[2];
  const float* Wv = (const float*)d_in[3];
  float* out = (float*)d_out;

  __bf16* Qb = (__bf16*)d_ws;                         // [B*S][64] pre-scaled
  __bf16* Kb = Qb + (size_t)B_N * S_N * D_N;          // [B*S][64]
  __bf16* Vt = Kb + (size_t)B_N * S_N * D_N;          // [B][64][S] transposed
  float* rZ = (float*)(Vt + (size_t)B_N * S_N * D_N); // [B,S]
  float* zP = rZ + (size_t)B_N * S_N;                 // [B,32,NCHUNK,4,64]
  __bf16* Wt = (__bf16*)(zP + (size_t)B_N * 32 * NCHUNK * 4 * 64); // [3][64][384]

  w_prep<<<dim3(3 * 64 * C_N / 256), dim3(256), 0, stream>>>(Wq, Wk, Wv, Wt);
  qkv_mfma<<<dim3(B_N * S_N / 32), dim3(384), 0, stream>>>(x, Wt, Qb, Kb, Vt);
  col_part<<<dim3(32 * NCHUNK * B_N), dim3(256), 0, stream>>>(Qb, Kb, zP);
  col_reduce<<<dim3(B_N * S_N / 256), dim3(256), 0, stream>>>(zP, rZ);
  attn_out<<<dim3(32 * B_N), dim3(1024), 0, stream>>>(Qb, Kb, Vt, rZ, out);
}

// Round 18
// 83.035 us; speedup vs baseline: 1.9657x; 1.0926x over previous
//
#include <hip/hip_runtime.h>
#include <hip/hip_bf16.h>
#include <math.h>

#define B_N 8
#define S_N 2048
#define C_N 384
#define D_N 64
#define NEG_BIG (-1e30f)

typedef __bf16 bf16x8 __attribute__((ext_vector_type(8)));
typedef float f32x4 __attribute__((ext_vector_type(4)));

static __device__ __forceinline__ bf16x8 ldfrag(const __bf16* p) {
  return *reinterpret_cast<const bf16x8*>(p);
}

// async 16B global -> LDS (linear dest, per-lane global src)
static __device__ __forceinline__ void gload16(void* lds, const void* gsrc) {
  __builtin_amdgcn_global_load_lds(
      (const __attribute__((address_space(1))) unsigned int*)gsrc,
      (__attribute__((address_space(3))) unsigned int*)lds, 16, 0, 0);
}

// ---------------------------------------------------------------------------
// Kernel 0: weight prep. Wt[m][d][c] = (bf16) W_m[c][d].
// ---------------------------------------------------------------------------
__global__ __launch_bounds__(256) void w_prep(
    const float* __restrict__ Wq, const float* __restrict__ Wk,
    const float* __restrict__ Wv, __bf16* __restrict__ Wt) {
  const int idx = blockIdx.x * 256 + threadIdx.x;   // [0, 3*64*384)
  const int m = idx / (64 * C_N);
  const int r = idx % (64 * C_N);
  const int d = r / C_N;
  const int c = r % C_N;
  const float* W = (m == 0) ? Wq : (m == 1) ? Wk : Wv;
  Wt[idx] = (__bf16)W[c * 64 + d];
}

// ---------------------------------------------------------------------------
// Kernel 1: QKV projection via MFMA (unchanged).
// ---------------------------------------------------------------------------
__global__ __launch_bounds__(384) void qkv_mfma(
    const float* __restrict__ x, const __bf16* __restrict__ Wt,
    __bf16* __restrict__ Q, __bf16* __restrict__ K, __bf16* __restrict__ Vt) {
  const int t = threadIdx.x;
  const int w = t >> 6, lane = t & 63, lr = lane & 15, lg = lane >> 4;
  const int mat = w >> 1, rh = w & 1;
  const int row0 = blockIdx.x * 32;                 // flat row in [0, B*S)
  const int ri = row0 + rh * 16 + lr;

  __shared__ __bf16 vtile[32][66];                  // V block, padded

  const float scl = (mat == 0) ? 0.125f : 1.0f;
  const float* xr = x + (size_t)ri * C_N;
  const __bf16* Wm = Wt + (size_t)mat * 64 * C_N;

  f32x4 acc[4];
#pragma unroll
  for (int nt = 0; nt < 4; ++nt) acc[nt] = {0.f, 0.f, 0.f, 0.f};

#pragma unroll 4
  for (int kk = 0; kk < C_N / 32; ++kk) {
    const float4 xa = *reinterpret_cast<const float4*>(xr + kk * 32 + lg * 8);
    const float4 xb = *reinterpret_cast<const float4*>(xr + kk * 32 + lg * 8 + 4);
    bf16x8 a;
    a[0] = (__bf16)(xa.x * scl); a[1] = (__bf16)(xa.y * scl);
    a[2] = (__bf16)(xa.z * scl); a[3] = (__bf16)(xa.w * scl);
    a[4] = (__bf16)(xb.x * scl); a[5] = (__bf16)(xb.y * scl);
    a[6] = (__bf16)(xb.z * scl); a[7] = (__bf16)(xb.w * scl);
#pragma unroll
    for (int nt = 0; nt < 4; ++nt) {
      const bf16x8 bw = ldfrag(Wm + (size_t)(nt * 16 + lr) * C_N + kk * 32 + lg * 8);
      acc[nt] = __builtin_amdgcn_mfma_f32_16x16x32_bf16(a, bw, acc[nt], 0, 0, 0);
    }
  }

  if (mat < 2) {
    __bf16* outp = (mat == 0) ? Q : K;
#pragma unroll
    for (int nt = 0; nt < 4; ++nt)
#pragma unroll
      for (int r = 0; r < 4; ++r)
        outp[(size_t)(row0 + rh * 16 + lg * 4 + r) * 64 + nt * 16 + lr] =
            (__bf16)acc[nt][r];
  } else {
#pragma unroll
    for (int nt = 0; nt < 4; ++nt)
#pragma unroll
      for (int r = 0; r < 4; ++r)
        vtile[rh * 16 + lg * 4 + r][nt * 16 + lr] = (__bf16)acc[nt][r];
  }
  __syncthreads();

  const int b = row0 >> 11, s0 = row0 & (S_N - 1);
  for (int idx = t; idx < 64 * 32; idx += 384) {
    const int d = idx >> 5, s2 = idx & 31;
    Vt[((size_t)b * D_N + d) * S_N + s0 + s2] = vtile[s2][d];
  }
}

// ---------------------------------------------------------------------------
// Kernel 2: column denominators (m == 0), flash-style staging. Block (b, jb),
// 16 waves: wave (s, q) = (i-strip, j-tile). K frags for j-tile q in regs
// (loaded once); Q tiles (8 KB) double-buffered via global_load_lds with
// source-swizzled chunks. One barrier per i-tile. Final 4-strip reduce in
// LDS; writes 1/Z directly (col_reduce kernel eliminated).
// ---------------------------------------------------------------------------
__global__ __launch_bounds__(1024) void col_stats(
    const __bf16* __restrict__ Q, const __bf16* __restrict__ K,
    float* __restrict__ rZ) {
  const int wg = blockIdx.x;                       // 256 blocks
  const int b  = wg & 7;                           // XCD swizzle
  const int jb = wg >> 3;                          // 0..31
  const int j0 = jb * 64;

  const int t = threadIdx.x;
  const int w = t >> 6;                            // wave 0..15
  const int s = w & 3;                             // i-strip (16 rows)
  const int q = w >> 2;                            // j-tile (16 cols)
  const int lane = t & 63, lr = lane & 15, lg = lane >> 4;

  __shared__ __align__(16) __bf16 QT[2][64][64];   // source-swizzled rows
  __shared__ float zs[4][4][16];                   // [strip][q][lr]

  const __bf16* Qb = Q + (size_t)b * S_N * 64;
  const __bf16* Kb = K + (size_t)b * S_N * 64;

  // K fragments for j-tile q (fixed for the whole block)
  const int krow = j0 + q * 16 + lr;
  const bf16x8 bk0 = ldfrag(Kb + (size_t)krow * 64 + lg * 8);
  const bf16x8 bk1 = ldfrag(Kb + (size_t)krow * 64 + 32 + lg * 8);

  // staging role: threads 0..511, one 16B chunk each (64 rows x 8 chunks)
  const int str  = t & 511;
  const int srow = str >> 3;
  const int schk = str & 7;
  const int gchk = schk ^ (srow & 7);              // inverse-swizzled source
  const bool stager = (t < 512);

  // prologue: stage i-tile it = jb into buffer 0
  if (stager)
    gload16(&QT[0][srow][schk * 8], Qb + (size_t)(j0 + srow) * 64 + gchk * 8);
  __syncthreads();

  float z = 0.f;
  int cur = 0;
  for (int it = jb; it < 32; ++it) {
    const int i0 = it * 64;
    if (it + 1 < 32 && stager)
      gload16(&QT[cur ^ 1][srow][schk * 8],
              Qb + (size_t)(i0 + 64 + srow) * 64 + gchk * 8);

    // A-frags from LDS: Q rows s*16+lr (swizzled chunks)
    const int arow = s * 16 + lr;
    const bf16x8 aq0 = ldfrag(&QT[cur][arow][(lg ^ (arow & 7)) * 8]);
    const bf16x8 aq1 = ldfrag(&QT[cur][arow][((4 + lg) ^ (arow & 7)) * 8]);

    f32x4 s4 = {0.f, 0.f, 0.f, 0.f};
    s4 = __builtin_amdgcn_mfma_f32_16x16x32_bf16(aq0, bk0, s4, 0, 0, 0);
    s4 = __builtin_amdgcn_mfma_f32_16x16x32_bf16(aq1, bk1, s4, 0, 0, 0);

    const int ibase = i0 + s * 16 + lg * 4;        // D-row base
    const int jg = j0 + q * 16 + lr;               // D col
    if (it == jb) {                                // diagonal tile: mask i < j
#pragma unroll
      for (int r = 0; r < 4; ++r)
        if (ibase + r < jg) s4[r] = NEG_BIG;       // expf -> 0
    }
    float es = __expf(s4[0]) + __expf(s4[1]) + __expf(s4[2]) + __expf(s4[3]);
    es += __shfl_xor(es, 16);
    es += __shfl_xor(es, 32);
    z += es;

    __syncthreads();   // QT[cur] reads done; next tile's DMA drained
    cur ^= 1;
  }

  if (lg == 0) zs[s][q][lr] = z;
  __syncthreads();
  if (s == 0 && lg == 0) {
    const float zt = zs[0][q][lr] + zs[1][q][lr] + zs[2][q][lr] + zs[3][q][lr];
    rZ[(size_t)b * S_N + j0 + q * 16 + lr] = 1.0f / zt;
  }
}

// ---------------------------------------------------------------------------
// Kernel 3: output pass, flash-style LDS staging (unchanged from R17).
// ---------------------------------------------------------------------------
__global__ __launch_bounds__(1024) void attn_out(
    const __bf16* __restrict__ Q, const __bf16* __restrict__ K,
    const __bf16* __restrict__ Vt, const float* __restrict__ rZ,
    float* __restrict__ out) {
  const int wg = blockIdx.x;                       // 256 blocks
  const int b  = wg & 7;                           // XCD swizzle
  const int ib = wg >> 3;                          // 0..31

  const int t = threadIdx.x;
  const int w = t >> 6;                            // wave 0..15
  const int s = w & 3;                             // strip (16 rows)
  const int q = w >> 2;                            // j-tile (QK) / d-quarter (PV)
  const int lane = t & 63, lr = lane & 15, lg = lane >> 4;
  const int i0 = ib * 64;

  __shared__ __align__(16) __bf16 KT[2][64][64];   // source-swizzled rows
  __shared__ __align__(16) __bf16 VT[2][64][64];   // source-swizzled rows
  __shared__ __align__(16) __bf16 P[4][16][72];    // P tiles, padded

  const __bf16* Qb  = Q  + (size_t)b * S_N * 64;
  const __bf16* Kb  = K  + (size_t)b * S_N * 64;
  const __bf16* Vtb = Vt + (size_t)b * D_N * S_N;
  const float*  rZb = rZ + (size_t)b * S_N;

  // staging role: waves 0-7 -> K rows, waves 8-15 -> V rows
  const int str  = t & 511;
  const int srow = str >> 3;                       // 0..63
  const int schk = str & 7;                        // 16B chunk within row
  const int gchk = schk ^ (srow & 7);              // inverse-swizzled source
  const bool isK = (t < 512);

  // Q fragments (registers, live whole kernel)
  const int ri = i0 + s * 16 + lr;
  const bf16x8 aq0 = ldfrag(Qb + (size_t)ri * 64 + lg * 8);
  const bf16x8 aq1 = ldfrag(Qb + (size_t)ri * 64 + 32 + lg * 8);
  const int ibase = i0 + s * 16 + lg * 4;          // D-row base

  f32x4 o = {0.f, 0.f, 0.f, 0.f};

  // prologue: stage tile jb=0 into buffer 0
  if (isK) gload16(&KT[0][srow][schk * 8], Kb + (size_t)srow * 64 + gchk * 8);
  else     gload16(&VT[0][srow][schk * 8], Vtb + (size_t)srow * S_N + gchk * 8);
  __syncthreads();

  int cur = 0;
  for (int jb = 0; jb <= ib; ++jb) {
    const int j0 = jb * 64;
    // ---- fire next tile's DMA (drains at the next barrier) ----
    if (jb + 1 <= ib) {
      const int j0n = j0 + 64;
      if (isK) gload16(&KT[cur ^ 1][srow][schk * 8],
                       Kb + (size_t)(j0n + srow) * 64 + gchk * 8);
      else     gload16(&VT[cur ^ 1][srow][schk * 8],
                       Vtb + (size_t)srow * S_N + j0n + gchk * 8);
    }

    // ---- QK: wave (s,q) computes strip s x j-tile q ----
    const int krow = q * 16 + lr;
    const bf16x8 bk0 = ldfrag(&KT[cur][krow][(lg ^ (krow & 7)) * 8]);
    const bf16x8 bk1 = ldfrag(&KT[cur][krow][((4 + lg) ^ (krow & 7)) * 8]);
    f32x4 s4 = {0.f, 0.f, 0.f, 0.f};
    s4 = __builtin_amdgcn_mfma_f32_16x16x32_bf16(aq0, bk0, s4, 0, 0, 0);
    s4 = __builtin_amdgcn_mfma_f32_16x16x32_bf16(aq1, bk1, s4, 0, 0, 0);

    const int jg = j0 + q * 16 + lr;               // D col
    const float rz = rZb[jg];
#pragma unroll
    for (int r = 0; r < 4; ++r) {
      const float pv = (jg <= ibase + r) ? __expf(s4[r]) * rz : 0.f;
      P[s][lg * 4 + r][q * 16 + lr] = (__bf16)pv;
    }
    __syncthreads();   // P visible; next tile's DMA drained

    // ---- PV: wave (s,q) accumulates strip s x d-quarter q ----
    const bf16x8 ap0 = ldfrag(&P[s][lr][lg * 8]);
    const bf16x8 ap1 = ldfrag(&P[s][lr][32 + lg * 8]);
    const int vrow = q * 16 + lr;
    const bf16x8 bv0 = ldfrag(&VT[cur][vrow][(lg ^ (vrow & 7)) * 8]);
    const bf16x8 bv1 = ldfrag(&VT[cur][vrow][((4 + lg) ^ (vrow & 7)) * 8]);
    o = __builtin_amdgcn_mfma_f32_16x16x32_bf16(ap0, bv0, o, 0, 0, 0);
    o = __builtin_amdgcn_mfma_f32_16x16x32_bf16(ap1, bv1, o, 0, 0, 0);
    __syncthreads();   // all reads of tile[cur] and P done
    cur ^= 1;
  }

  float* ob = out + (size_t)b * S_N * D_N;
#pragma unroll
  for (int r = 0; r < 4; ++r)
    ob[(size_t)(i0 + s * 16 + lg * 4 + r) * 64 + q * 16 + lr] = o[r];
}

extern "C" void kernel_launch(void* const* d_in, const int* in_sizes, int n_in,
                              void* d_out, int out_size, void* d_ws, size_t ws_size,
                              hipStream_t stream) {
  (void)in_sizes; (void)n_in; (void)ws_size; (void)out_size;
  const float* x  = (const float*)d_in[0];
  const float* Wq = (const float*)d_in[1];
  const float* Wk = (const float*)d_in[2];
  const float* Wv = (const float*)d_in[3];
  float* out = (float*)d_out;

  __bf16* Qb = (__bf16*)d_ws;                         // [B*S][64] pre-scaled
  __bf16* Kb = Qb + (size_t)B_N * S_N * D_N;          // [B*S][64]
  __bf16* Vt = Kb + (size_t)B_N * S_N * D_N;          // [B][64][S] transposed
  float* rZ = (float*)(Vt + (size_t)B_N * S_N * D_N); // [B,S]
  __bf16* Wt = (__bf16*)(rZ + (size_t)B_N * S_N);     // [3][64][384]

  w_prep<<<dim3(3 * 64 * C_N / 256), dim3(256), 0, stream>>>(Wq, Wk, Wv, Wt);
  qkv_mfma<<<dim3(B_N * S_N / 32), dim3(384), 0, stream>>>(x, Wt, Qb, Kb, Vt);
  col_stats<<<dim3(32 * B_N), dim3(1024), 0, stream>>>(Qb, Kb, rZ);
  attn_out<<<dim3(32 * B_N), dim3(1024), 0, stream>>>(Qb, Kb, Vt, rZ, out);
}

// Round 19
// 76.964 us; speedup vs baseline: 2.1208x; 1.0789x over previous
//
#include <hip/hip_runtime.h>
#include <hip/hip_bf16.h>
#include <math.h>

#define B_N 8
#define S_N 2048
#define C_N 384
#define D_N 64
#define NEG_BIG (-1e30f)

typedef __bf16 bf16x8 __attribute__((ext_vector_type(8)));
typedef float f32x4 __attribute__((ext_vector_type(4)));

static __device__ __forceinline__ bf16x8 ldfrag(const __bf16* p) {
  return *reinterpret_cast<const bf16x8*>(p);
}

// async 16B global -> LDS (linear dest, per-lane global src)
static __device__ __forceinline__ void gload16(void* lds, const void* gsrc) {
  __builtin_amdgcn_global_load_lds(
      (const __attribute__((address_space(1))) unsigned int*)gsrc,
      (__attribute__((address_space(3))) unsigned int*)lds, 16, 0, 0);
}

// ---------------------------------------------------------------------------
// Kernel 0: weight prep. Wt[m][d][c] = (bf16) W_m[c][d].
// ---------------------------------------------------------------------------
__global__ __launch_bounds__(256) void w_prep(
    const float* __restrict__ Wq, const float* __restrict__ Wk,
    const float* __restrict__ Wv, __bf16* __restrict__ Wt) {
  const int idx = blockIdx.x * 256 + threadIdx.x;   // [0, 3*64*384)
  const int m = idx / (64 * C_N);
  const int r = idx % (64 * C_N);
  const int d = r / C_N;
  const int c = r % C_N;
  const float* W = (m == 0) ? Wq : (m == 1) ? Wk : Wv;
  Wt[idx] = (__bf16)W[c * 64 + d];
}

// ---------------------------------------------------------------------------
// Kernel 1: QKV projection via MFMA, x and W register-prefetched across k.
// ---------------------------------------------------------------------------
__global__ __launch_bounds__(384) void qkv_mfma(
    const float* __restrict__ x, const __bf16* __restrict__ Wt,
    __bf16* __restrict__ Q, __bf16* __restrict__ K, __bf16* __restrict__ Vt) {
  const int t = threadIdx.x;
  const int w = t >> 6, lane = t & 63, lr = lane & 15, lg = lane >> 4;
  const int mat = w >> 1, rh = w & 1;
  const int row0 = blockIdx.x * 32;                 // flat row in [0, B*S)
  const int ri = row0 + rh * 16 + lr;

  __shared__ __bf16 vtile[32][66];                  // V block, padded

  const float scl = (mat == 0) ? 0.125f : 1.0f;
  const float* xr = x + (size_t)ri * C_N;
  const __bf16* Wm = Wt + (size_t)mat * 64 * C_N;

  f32x4 acc[4];
#pragma unroll
  for (int nt = 0; nt < 4; ++nt) acc[nt] = {0.f, 0.f, 0.f, 0.f};

  // prefetch k=0
  float4 xa = *reinterpret_cast<const float4*>(xr + lg * 8);
  float4 xb = *reinterpret_cast<const float4*>(xr + lg * 8 + 4);
  bf16x8 bw[4];
#pragma unroll
  for (int nt = 0; nt < 4; ++nt)
    bw[nt] = ldfrag(Wm + (size_t)(nt * 16 + lr) * C_N + lg * 8);

  for (int kk = 0; kk < C_N / 32; ++kk) {
    const int kn = (kk + 1 < C_N / 32) ? kk + 1 : kk;
    const float4 xan = *reinterpret_cast<const float4*>(xr + kn * 32 + lg * 8);
    const float4 xbn = *reinterpret_cast<const float4*>(xr + kn * 32 + lg * 8 + 4);
    bf16x8 bwn[4];
#pragma unroll
    for (int nt = 0; nt < 4; ++nt)
      bwn[nt] = ldfrag(Wm + (size_t)(nt * 16 + lr) * C_N + kn * 32 + lg * 8);

    bf16x8 a;
    a[0] = (__bf16)(xa.x * scl); a[1] = (__bf16)(xa.y * scl);
    a[2] = (__bf16)(xa.z * scl); a[3] = (__bf16)(xa.w * scl);
    a[4] = (__bf16)(xb.x * scl); a[5] = (__bf16)(xb.y * scl);
    a[6] = (__bf16)(xb.z * scl); a[7] = (__bf16)(xb.w * scl);
#pragma unroll
    for (int nt = 0; nt < 4; ++nt)
      acc[nt] = __builtin_amdgcn_mfma_f32_16x16x32_bf16(a, bw[nt], acc[nt], 0, 0, 0);

    xa = xan; xb = xbn;
#pragma unroll
    for (int nt = 0; nt < 4; ++nt) bw[nt] = bwn[nt];
  }

  if (mat < 2) {
    __bf16* outp = (mat == 0) ? Q : K;
#pragma unroll
    for (int nt = 0; nt < 4; ++nt)
#pragma unroll
      for (int r = 0; r < 4; ++r)
        outp[(size_t)(row0 + rh * 16 + lg * 4 + r) * 64 + nt * 16 + lr] =
            (__bf16)acc[nt][r];
  } else {
#pragma unroll
    for (int nt = 0; nt < 4; ++nt)
#pragma unroll
      for (int r = 0; r < 4; ++r)
        vtile[rh * 16 + lg * 4 + r][nt * 16 + lr] = (__bf16)acc[nt][r];
  }
  __syncthreads();

  const int b = row0 >> 11, s0 = row0 & (S_N - 1);
  for (int idx = t; idx < 64 * 32; idx += 384) {
    const int d = idx >> 5, s2 = idx & 31;
    Vt[((size_t)b * D_N + d) * S_N + s0 + s2] = vtile[s2][d];
  }
}

// ---------------------------------------------------------------------------
// Kernel 2: column denominator PARTIALS (m == 0). Grid (b, jb, h): h splits
// the i-scan in half -> worst block 16 iterations, 2 blocks/CU. Writes plain
// partial sums zpart[h][b][j]; attn_out computes 1/(z0+z1) on the fly.
// ---------------------------------------------------------------------------
__global__ __launch_bounds__(1024) void col_stats(
    const __bf16* __restrict__ Q, const __bf16* __restrict__ K,
    float* __restrict__ zpart) {
  const int wg = blockIdx.x;                       // 512 blocks
  const int b  = wg & 7;                           // XCD swizzle
  const int jb = (wg >> 3) & 31;                   // 0..31
  const int h  = wg >> 8;                          // 0..1
  const int j0 = jb * 64;

  const int t = threadIdx.x;
  const int w = t >> 6;                            // wave 0..15
  const int s = w & 3;                             // i-strip (16 rows)
  const int q = w >> 2;                            // j-tile (16 cols)
  const int lane = t & 63, lr = lane & 15, lg = lane >> 4;

  const int n = 32 - jb;                           // tiles in the full scan
  const int itStart = (h == 0) ? jb : jb + (n + 1) / 2;
  const int itEnd   = (h == 0) ? jb + (n + 1) / 2 : 32;
  float* zout = zpart + (size_t)h * B_N * S_N + (size_t)b * S_N;

  __shared__ __align__(16) __bf16 QT[2][64][64];   // source-swizzled rows
  __shared__ float zs[4][4][16];                   // [strip][q][lr]

  if (itStart >= itEnd) {                          // empty half: zero partials
    if (w == 0 && lg == 0) {
      // q==0 here; write all 64 columns with 16 lanes x 4 slots
      for (int c = lr; c < 64; c += 16) zout[j0 + c] = 0.f;
    }
    return;
  }

  const __bf16* Qb = Q + (size_t)b * S_N * 64;
  const __bf16* Kb = K + (size_t)b * S_N * 64;

  // K fragments for j-tile q (fixed for the whole block)
  const int krow = j0 + q * 16 + lr;
  const bf16x8 bk0 = ldfrag(Kb + (size_t)krow * 64 + lg * 8);
  const bf16x8 bk1 = ldfrag(Kb + (size_t)krow * 64 + 32 + lg * 8);

  // staging role: threads 0..511, one 16B chunk each (64 rows x 8 chunks)
  const int str  = t & 511;
  const int srow = str >> 3;
  const int schk = str & 7;
  const int gchk = schk ^ (srow & 7);              // inverse-swizzled source
  const bool stager = (t < 512);

  if (stager)
    gload16(&QT[0][srow][schk * 8],
            Qb + (size_t)(itStart * 64 + srow) * 64 + gchk * 8);
  __syncthreads();

  float z = 0.f;
  int cur = 0;
  for (int it = itStart; it < itEnd; ++it) {
    const int i0 = it * 64;
    if (it + 1 < itEnd && stager)
      gload16(&QT[cur ^ 1][srow][schk * 8],
              Qb + (size_t)(i0 + 64 + srow) * 64 + gchk * 8);

    const int arow = s * 16 + lr;
    const bf16x8 aq0 = ldfrag(&QT[cur][arow][(lg ^ (arow & 7)) * 8]);
    const bf16x8 aq1 = ldfrag(&QT[cur][arow][((4 + lg) ^ (arow & 7)) * 8]);

    f32x4 s4 = {0.f, 0.f, 0.f, 0.f};
    s4 = __builtin_amdgcn_mfma_f32_16x16x32_bf16(aq0, bk0, s4, 0, 0, 0);
    s4 = __builtin_amdgcn_mfma_f32_16x16x32_bf16(aq1, bk1, s4, 0, 0, 0);

    const int ibase = i0 + s * 16 + lg * 4;        // D-row base
    const int jg = j0 + q * 16 + lr;               // D col
    if (it == jb) {                                // diag only ever in h==0
#pragma unroll
      for (int r = 0; r < 4; ++r)
        if (ibase + r < jg) s4[r] = NEG_BIG;       // expf -> 0
    }
    float es = __expf(s4[0]) + __expf(s4[1]) + __expf(s4[2]) + __expf(s4[3]);
    es += __shfl_xor(es, 16);
    es += __shfl_xor(es, 32);
    z += es;

    __syncthreads();   // QT[cur] reads done; next tile's DMA drained
    cur ^= 1;
  }

  if (lg == 0) zs[s][q][lr] = z;
  __syncthreads();
  if (s == 0 && lg == 0) {
    const float zt = zs[0][q][lr] + zs[1][q][lr] + zs[2][q][lr] + zs[3][q][lr];
    zout[j0 + q * 16 + lr] = zt;
  }
}

// ---------------------------------------------------------------------------
// Kernel 3: output pass PARTIALS. Grid (b, ib, h): h splits the j-scan in
// half -> worst block 16 iterations, 2 blocks/CU. rz = 1/(z0+z1) on the fly.
// Each half writes disjoint f32 partials opart[h][b][i][d] (plain stores).
// ---------------------------------------------------------------------------
__global__ __launch_bounds__(1024) void attn_out(
    const __bf16* __restrict__ Q, const __bf16* __restrict__ K,
    const __bf16* __restrict__ Vt, const float* __restrict__ zpart,
    float* __restrict__ opart) {
  const int wg = blockIdx.x;                       // 512 blocks
  const int b  = wg & 7;                           // XCD swizzle
  const int ib = (wg >> 3) & 31;                   // 0..31
  const int h  = wg >> 8;                          // 0..1

  const int t = threadIdx.x;
  const int w = t >> 6;                            // wave 0..15
  const int s = w & 3;                             // strip (16 rows)
  const int q = w >> 2;                            // j-tile (QK) / d-quarter (PV)
  const int lane = t & 63, lr = lane & 15, lg = lane >> 4;
  const int i0 = ib * 64;

  const int n = ib + 1;
  const int jbStart = (h == 0) ? 0 : (n + 1) / 2;
  const int jbEnd   = (h == 0) ? (n + 1) / 2 : n;

  float* op = opart + (size_t)h * B_N * S_N * D_N + (size_t)b * S_N * D_N;

  if (jbStart >= jbEnd) {                          // empty half: zero partials
#pragma unroll
    for (int r = 0; r < 4; ++r)
      op[(size_t)(i0 + s * 16 + lg * 4 + r) * 64 + q * 16 + lr] = 0.f;
    return;
  }

  __shared__ __align__(16) __bf16 KT[2][64][64];   // source-swizzled rows
  __shared__ __align__(16) __bf16 VT[2][64][64];   // source-swizzled rows
  __shared__ __align__(16) __bf16 P[4][16][72];    // P tiles, padded

  const __bf16* Qb  = Q  + (size_t)b * S_N * 64;
  const __bf16* Kb  = K  + (size_t)b * S_N * 64;
  const __bf16* Vtb = Vt + (size_t)b * D_N * S_N;
  const float*  zp0 = zpart + (size_t)b * S_N;
  const float*  zp1 = zpart + (size_t)B_N * S_N + (size_t)b * S_N;

  // staging role: waves 0-7 -> K rows, waves 8-15 -> V rows
  const int str  = t & 511;
  const int srow = str >> 3;                       // 0..63
  const int schk = str & 7;                        // 16B chunk within row
  const int gchk = schk ^ (srow & 7);              // inverse-swizzled source
  const bool isK = (t < 512);

  // Q fragments (registers, live whole kernel)
  const int ri = i0 + s * 16 + lr;
  const bf16x8 aq0 = ldfrag(Qb + (size_t)ri * 64 + lg * 8);
  const bf16x8 aq1 = ldfrag(Qb + (size_t)ri * 64 + 32 + lg * 8);
  const int ibase = i0 + s * 16 + lg * 4;          // D-row base

  f32x4 o = {0.f, 0.f, 0.f, 0.f};

  // prologue: stage tile jbStart into buffer 0
  if (isK) gload16(&KT[0][srow][schk * 8],
                   Kb + (size_t)(jbStart * 64 + srow) * 64 + gchk * 8);
  else     gload16(&VT[0][srow][schk * 8],
                   Vtb + (size_t)srow * S_N + jbStart * 64 + gchk * 8);
  __syncthreads();

  int cur = 0;
  for (int jb = jbStart; jb < jbEnd; ++jb) {
    const int j0 = jb * 64;
    // ---- fire next tile's DMA (drains at the next barrier) ----
    if (jb + 1 < jbEnd) {
      const int j0n = j0 + 64;
      if (isK) gload16(&KT[cur ^ 1][srow][schk * 8],
                       Kb + (size_t)(j0n + srow) * 64 + gchk * 8);
      else     gload16(&VT[cur ^ 1][srow][schk * 8],
                       Vtb + (size_t)srow * S_N + j0n + gchk * 8);
    }

    // ---- QK: wave (s,q) computes strip s x j-tile q ----
    const int krow = q * 16 + lr;
    const bf16x8 bk0 = ldfrag(&KT[cur][krow][(lg ^ (krow & 7)) * 8]);
    const bf16x8 bk1 = ldfrag(&KT[cur][krow][((4 + lg) ^ (krow & 7)) * 8]);
    f32x4 s4 = {0.f, 0.f, 0.f, 0.f};
    s4 = __builtin_amdgcn_mfma_f32_16x16x32_bf16(aq0, bk0, s4, 0, 0, 0);
    s4 = __builtin_amdgcn_mfma_f32_16x16x32_bf16(aq1, bk1, s4, 0, 0, 0);

    const int jg = j0 + q * 16 + lr;               // D col
    const float rz = 1.0f / (zp0[jg] + zp1[jg]);
#pragma unroll
    for (int r = 0; r < 4; ++r) {
      const float pv = (jg <= ibase + r) ? __expf(s4[r]) * rz : 0.f;
      P[s][lg * 4 + r][q * 16 + lr] = (__bf16)pv;
    }
    __syncthreads();   // P visible; next tile's DMA drained

    // ---- PV: wave (s,q) accumulates strip s x d-quarter q ----
    const bf16x8 ap0 = ldfrag(&P[s][lr][lg * 8]);
    const bf16x8 ap1 = ldfrag(&P[s][lr][32 + lg * 8]);
    const int vrow = q * 16 + lr;
    const bf16x8 bv0 = ldfrag(&VT[cur][vrow][(lg ^ (vrow & 7)) * 8]);
    const bf16x8 bv1 = ldfrag(&VT[cur][vrow][((4 + lg) ^ (vrow & 7)) * 8]);
    o = __builtin_amdgcn_mfma_f32_16x16x32_bf16(ap0, bv0, o, 0, 0, 0);
    o = __builtin_amdgcn_mfma_f32_16x16x32_bf16(ap1, bv1, o, 0, 0, 0);
    __syncthreads();   // all reads of tile[cur] and P done
    cur ^= 1;
  }

#pragma unroll
  for (int r = 0; r < 4; ++r)
    op[(size_t)(i0 + s * 16 + lg * 4 + r) * 64 + q * 16 + lr] = o[r];
}

// ---------------------------------------------------------------------------
// Kernel 4: combine the two attn_out halves. out = op0 + op1.
// ---------------------------------------------------------------------------
__global__ __launch_bounds__(256) void combine(
    const float* __restrict__ opart, float* __restrict__ out) {
  const size_t idx = (size_t)blockIdx.x * 256 + threadIdx.x;
  out[idx] = opart[idx] + opart[(size_t)B_N * S_N * D_N + idx];
}

extern "C" void kernel_launch(void* const* d_in, const int* in_sizes, int n_in,
                              void* d_out, int out_size, void* d_ws, size_t ws_size,
                              hipStream_t stream) {
  (void)in_sizes; (void)n_in; (void)ws_size; (void)out_size;
  const float* x  = (const float*)d_in[0];
  const float* Wq = (const float*)d_in[1];
  const float* Wk = (const float*)d_in[2];
  const float* Wv = (const float*)d_in[3];
  float* out = (float*)d_out;

  __bf16* Qb = (__bf16*)d_ws;                         // [B*S][64] pre-scaled
  __bf16* Kb = Qb + (size_t)B_N * S_N * D_N;          // [B*S][64]
  __bf16* Vt = Kb + (size_t)B_N * S_N * D_N;          // [B][64][S] transposed
  float* zpart = (float*)(Vt + (size_t)B_N * S_N * D_N); // [2][B][S]
  float* opart = zpart + (size_t)2 * B_N * S_N;          // [2][B][S][64]
  __bf16* Wt = (__bf16*)(opart + (size_t)2 * B_N * S_N * D_N); // [3][64][384]

  w_prep<<<dim3(3 * 64 * C_N / 256), dim3(256), 0, stream>>>(Wq, Wk, Wv, Wt);
  qkv_mfma<<<dim3(B_N * S_N / 32), dim3(384), 0, stream>>>(x, Wt, Qb, Kb, Vt);
  col_stats<<<dim3(2 * 32 * B_N), dim3(1024), 0, stream>>>(Qb, Kb, zpart);
  attn_out<<<dim3(2 * 32 * B_N), dim3(1024), 0, stream>>>(Qb, Kb, Vt, zpart, opart);
  combine<<<dim3(B_N * S_N * D_N / 256), dim3(256), 0, stream>>>(opart, out);
}

// Round 21
// 74.480 us; speedup vs baseline: 2.1915x; 1.0334x over previous
//
#include <hip/hip_runtime.h>
#include <hip/hip_bf16.h>
#include <math.h>

#define B_N 8
#define S_N 2048
#define C_N 384
#define D_N 64
#define NPART 4           // triangular split factor
#define NEG_BIG (-1e30f)

typedef __bf16 bf16x8 __attribute__((ext_vector_type(8)));
typedef float f32x4 __attribute__((ext_vector_type(4)));

static __device__ __forceinline__ bf16x8 ldfrag(const __bf16* p) {
  return *reinterpret_cast<const bf16x8*>(p);
}

// async 16B global -> LDS (linear dest, per-lane global src)
static __device__ __forceinline__ void gload16(void* lds, const void* gsrc) {
  __builtin_amdgcn_global_load_lds(
      (const __attribute__((address_space(1))) unsigned int*)gsrc,
      (__attribute__((address_space(3))) unsigned int*)lds, 16, 0, 0);
}

// ---------------------------------------------------------------------------
// Kernel 0: weight prep. Wt[m][d][c] = (bf16) W_m[c][d].
// ---------------------------------------------------------------------------
__global__ __launch_bounds__(256) void w_prep(
    const float* __restrict__ Wq, const float* __restrict__ Wk,
    const float* __restrict__ Wv, __bf16* __restrict__ Wt) {
  const int idx = blockIdx.x * 256 + threadIdx.x;   // [0, 3*64*384)
  const int m = idx / (64 * C_N);
  const int r = idx % (64 * C_N);
  const int d = r / C_N;
  const int c = r % C_N;
  const float* W = (m == 0) ? Wq : (m == 1) ? Wk : Wv;
  Wt[idx] = (__bf16)W[c * 64 + d];
}

// ---------------------------------------------------------------------------
// Kernel 1: QKV projection via MFMA, x and W register-prefetched (R19).
// ---------------------------------------------------------------------------
__global__ __launch_bounds__(384) void qkv_mfma(
    const float* __restrict__ x, const __bf16* __restrict__ Wt,
    __bf16* __restrict__ Q, __bf16* __restrict__ K, __bf16* __restrict__ Vt) {
  const int t = threadIdx.x;
  const int w = t >> 6, lane = t & 63, lr = lane & 15, lg = lane >> 4;
  const int mat = w >> 1, rh = w & 1;
  const int row0 = blockIdx.x * 32;                 // flat row in [0, B*S)
  const int ri = row0 + rh * 16 + lr;

  __shared__ __bf16 vtile[32][66];                  // V block, padded

  const float scl = (mat == 0) ? 0.125f : 1.0f;
  const float* xr = x + (size_t)ri * C_N;
  const __bf16* Wm = Wt + (size_t)mat * 64 * C_N;

  f32x4 acc[4];
#pragma unroll
  for (int nt = 0; nt < 4; ++nt) acc[nt] = {0.f, 0.f, 0.f, 0.f};

  float4 xa = *reinterpret_cast<const float4*>(xr + lg * 8);
  float4 xb = *reinterpret_cast<const float4*>(xr + lg * 8 + 4);
  bf16x8 bw[4];
#pragma unroll
  for (int nt = 0; nt < 4; ++nt)
    bw[nt] = ldfrag(Wm + (size_t)(nt * 16 + lr) * C_N + lg * 8);

  for (int kk = 0; kk < C_N / 32; ++kk) {
    const int kn = (kk + 1 < C_N / 32) ? kk + 1 : kk;
    const float4 xan = *reinterpret_cast<const float4*>(xr + kn * 32 + lg * 8);
    const float4 xbn = *reinterpret_cast<const float4*>(xr + kn * 32 + lg * 8 + 4);
    bf16x8 bwn[4];
#pragma unroll
    for (int nt = 0; nt < 4; ++nt)
      bwn[nt] = ldfrag(Wm + (size_t)(nt * 16 + lr) * C_N + kn * 32 + lg * 8);

    bf16x8 a;
    a[0] = (__bf16)(xa.x * scl); a[1] = (__bf16)(xa.y * scl);
    a[2] = (__bf16)(xa.z * scl); a[3] = (__bf16)(xa.w * scl);
    a[4] = (__bf16)(xb.x * scl); a[5] = (__bf16)(xb.y * scl);
    a[6] = (__bf16)(xb.z * scl); a[7] = (__bf16)(xb.w * scl);
#pragma unroll
    for (int nt = 0; nt < 4; ++nt)
      acc[nt] = __builtin_amdgcn_mfma_f32_16x16x32_bf16(a, bw[nt], acc[nt], 0, 0, 0);

    xa = xan; xb = xbn;
#pragma unroll
    for (int nt = 0; nt < 4; ++nt) bw[nt] = bwn[nt];
  }

  if (mat < 2) {
    __bf16* outp = (mat == 0) ? Q : K;
#pragma unroll
    for (int nt = 0; nt < 4; ++nt)
#pragma unroll
      for (int r = 0; r < 4; ++r)
        outp[(size_t)(row0 + rh * 16 + lg * 4 + r) * 64 + nt * 16 + lr] =
            (__bf16)acc[nt][r];
  } else {
#pragma unroll
    for (int nt = 0; nt < 4; ++nt)
#pragma unroll
      for (int r = 0; r < 4; ++r)
        vtile[rh * 16 + lg * 4 + r][nt * 16 + lr] = (__bf16)acc[nt][r];
  }
  __syncthreads();

  const int b = row0 >> 11, s0 = row0 & (S_N - 1);
  for (int idx = t; idx < 64 * 32; idx += 384) {
    const int d = idx >> 5, s2 = idx & 31;
    Vt[((size_t)b * D_N + d) * S_N + s0 + s2] = vtile[s2][d];
  }
}

// ---------------------------------------------------------------------------
// Kernel 2: column denominator PARTIALS (m == 0). Grid (b, jb, h), 256 thr =
// 4 waves; wave q owns j-tile q over ALL 4 i-strips -> z stays in registers,
// no cross-wave sharing. ONE 4-wave barrier per i-tile; DMA issued right
// after it has the whole iteration to land.
// ---------------------------------------------------------------------------
__global__ __launch_bounds__(256) void col_stats(
    const __bf16* __restrict__ Q, const __bf16* __restrict__ K,
    float* __restrict__ zpart) {
  const int wg = blockIdx.x;                       // 1024 blocks
  const int b  = wg & 7;                           // XCD swizzle
  const int jb = (wg >> 3) & 31;                   // 0..31
  const int h  = wg >> 8;                          // 0..3
  const int j0 = jb * 64;

  const int t = threadIdx.x;
  const int q = t >> 6;                            // wave = j-tile 0..3
  const int lane = t & 63, lr = lane & 15, lg = lane >> 4;

  const int n = 32 - jb;
  const int itStart = jb + (n * h) / NPART;
  const int itEnd   = jb + (n * (h + 1)) / NPART;
  float* zout = zpart + (size_t)h * B_N * S_N + (size_t)b * S_N;

  if (itStart >= itEnd) {                          // empty part: zero partials
    if (lg == 0) zout[j0 + q * 16 + lr] = 0.f;
    return;
  }

  __shared__ __align__(16) __bf16 QT[2][64][64];   // source-swizzled rows

  const __bf16* Qb = Q + (size_t)b * S_N * 64;
  const __bf16* Kb = K + (size_t)b * S_N * 64;

  // K fragments for j-tile q (fixed for the whole block)
  const int krow = j0 + q * 16 + lr;
  const bf16x8 bk0 = ldfrag(Kb + (size_t)krow * 64 + lg * 8);
  const bf16x8 bk1 = ldfrag(Kb + (size_t)krow * 64 + 32 + lg * 8);

  // staging: 512 chunks / 256 threads = 2 each (rows r0 and r0+32)
  const int r0 = t >> 3, c0 = t & 7;
  const int gq = c0 ^ (r0 & 7);                    // same for r0+32

#define STAGE_Q(BUF, TILE) do { \
    gload16(&QT[BUF][r0][c0 * 8], Qb + (size_t)((TILE) * 64 + r0) * 64 + gq * 8); \
    gload16(&QT[BUF][r0 + 32][c0 * 8], \
            Qb + (size_t)((TILE) * 64 + r0 + 32) * 64 + gq * 8); \
  } while (0)

  STAGE_Q(0, itStart);
  __syncthreads();

  float z = 0.f;
  int cur = 0;
  for (int it = itStart; it < itEnd; ++it) {
    const int i0 = it * 64;
    if (it + 1 < itEnd) STAGE_Q(cur ^ 1, it + 1);  // full iteration to land

#pragma unroll
    for (int s = 0; s < 4; ++s) {
      const int arow = s * 16 + lr;
      const bf16x8 aq0 = ldfrag(&QT[cur][arow][(lg ^ (arow & 7)) * 8]);
      const bf16x8 aq1 = ldfrag(&QT[cur][arow][((4 + lg) ^ (arow & 7)) * 8]);
      f32x4 s4 = {0.f, 0.f, 0.f, 0.f};
      s4 = __builtin_amdgcn_mfma_f32_16x16x32_bf16(aq0, bk0, s4, 0, 0, 0);
      s4 = __builtin_amdgcn_mfma_f32_16x16x32_bf16(aq1, bk1, s4, 0, 0, 0);
      const int ibase = i0 + s * 16 + lg * 4;      // D-row base
      const int jg = j0 + q * 16 + lr;             // D col
      if (it == jb) {                              // diagonal tile mask
#pragma unroll
        for (int r = 0; r < 4; ++r)
          if (ibase + r < jg) s4[r] = NEG_BIG;     // expf -> 0
      }
      float es = __expf(s4[0]) + __expf(s4[1]) + __expf(s4[2]) + __expf(s4[3]);
      es += __shfl_xor(es, 16);
      es += __shfl_xor(es, 32);
      z += es;
    }

    __syncthreads();   // QT[cur] reads done; next tile's DMA drained
    cur ^= 1;
  }
#undef STAGE_Q

  if (lg == 0) zout[j0 + q * 16 + lr] = z;         // wave-local, no barrier
}

// ---------------------------------------------------------------------------
// Kernel 3: output pass PARTIALS. Grid (b, ib, h), 256 thr = 4 waves; wave s
// owns strip s: computes the strip's FULL P (private LDS region, same-wave
// DS ordering) and the full PV (o[4] accumulators). ONE 4-wave barrier per
// jb-tile. rz = 1/sum(zpart) on the fly; disjoint f32 partial stores.
// ---------------------------------------------------------------------------
__global__ __launch_bounds__(256) void attn_out(
    const __bf16* __restrict__ Q, const __bf16* __restrict__ K,
    const __bf16* __restrict__ Vt, const float* __restrict__ zpart,
    float* __restrict__ opart) {
  const int wg = blockIdx.x;                       // 1024 blocks
  const int b  = wg & 7;                           // XCD swizzle
  const int ib = (wg >> 3) & 31;                   // 0..31
  const int h  = wg >> 8;                          // 0..3

  const int t = threadIdx.x;
  const int s = t >> 6;                            // wave = strip 0..3
  const int lane = t & 63, lr = lane & 15, lg = lane >> 4;
  const int i0 = ib * 64;

  const int n = ib + 1;
  const int jbStart = (n * h) / NPART;
  const int jbEnd   = (n * (h + 1)) / NPART;

  float* op = opart + (size_t)h * B_N * S_N * D_N + (size_t)b * S_N * D_N;
  const int ibase = i0 + s * 16 + lg * 4;          // D-row base

  f32x4 o[4];
#pragma unroll
  for (int dt = 0; dt < 4; ++dt) o[dt] = {0.f, 0.f, 0.f, 0.f};

  if (jbStart < jbEnd) {
    __shared__ __align__(16) __bf16 KT[2][64][64];
    __shared__ __align__(16) __bf16 VT[2][64][64];
    __shared__ __align__(16) __bf16 P[4][16][72];  // per-wave private strips

    const __bf16* Qb  = Q  + (size_t)b * S_N * 64;
    const __bf16* Kb  = K  + (size_t)b * S_N * 64;
    const __bf16* Vtb = Vt + (size_t)b * D_N * S_N;
    const float*  zp  = zpart + (size_t)b * S_N;

    // staging: 1024 chunks / 256 threads = 4 each (K r0, r0+32; V r0, r0+32)
    const int r0 = t >> 3, c0 = t & 7;
    const int gq = c0 ^ (r0 & 7);

#define STAGE_KV(BUF, TJ0) do { \
      gload16(&KT[BUF][r0][c0 * 8], Kb + (size_t)((TJ0) + r0) * 64 + gq * 8); \
      gload16(&KT[BUF][r0 + 32][c0 * 8], \
              Kb + (size_t)((TJ0) + r0 + 32) * 64 + gq * 8); \
      gload16(&VT[BUF][r0][c0 * 8], Vtb + (size_t)r0 * S_N + (TJ0) + gq * 8); \
      gload16(&VT[BUF][r0 + 32][c0 * 8], \
              Vtb + (size_t)(r0 + 32) * S_N + (TJ0) + gq * 8); \
    } while (0)

    // Q fragments (registers, live whole kernel)
    const int ri = i0 + s * 16 + lr;
    const bf16x8 aq0 = ldfrag(Qb + (size_t)ri * 64 + lg * 8);
    const bf16x8 aq1 = ldfrag(Qb + (size_t)ri * 64 + 32 + lg * 8);

    STAGE_KV(0, jbStart * 64);
    __syncthreads();

    int cur = 0;
    for (int jb = jbStart; jb < jbEnd; ++jb) {
      const int j0 = jb * 64;
      if (jb + 1 < jbEnd) STAGE_KV(cur ^ 1, j0 + 64);  // full iteration to land

      // ---- QK + P for the whole strip (wave-local) ----
#pragma unroll
      for (int jt = 0; jt < 4; ++jt) {
        const int krow = jt * 16 + lr;
        const bf16x8 bk0 = ldfrag(&KT[cur][krow][(lg ^ (krow & 7)) * 8]);
        const bf16x8 bk1 = ldfrag(&KT[cur][krow][((4 + lg) ^ (krow & 7)) * 8]);
        f32x4 s4 = {0.f, 0.f, 0.f, 0.f};
        s4 = __builtin_amdgcn_mfma_f32_16x16x32_bf16(aq0, bk0, s4, 0, 0, 0);
        s4 = __builtin_amdgcn_mfma_f32_16x16x32_bf16(aq1, bk1, s4, 0, 0, 0);
        const int jg = j0 + jt * 16 + lr;          // D col
        const float rz = 1.0f / (zp[jg] + zp[(size_t)B_N * S_N + jg] +
                                 zp[(size_t)2 * B_N * S_N + jg] +
                                 zp[(size_t)3 * B_N * S_N + jg]);
#pragma unroll
        for (int r = 0; r < 4; ++r) {
          const float pv = (jg <= ibase + r) ? __expf(s4[r]) * rz : 0.f;
          P[s][lg * 4 + r][jt * 16 + lr] = (__bf16)pv;
        }
      }

      // ---- PV from own P strip (same-wave DS ordering, no barrier) ----
      const bf16x8 ap0 = ldfrag(&P[s][lr][lg * 8]);
      const bf16x8 ap1 = ldfrag(&P[s][lr][32 + lg * 8]);
#pragma unroll
      for (int dt = 0; dt < 4; ++dt) {
        const int vrow = dt * 16 + lr;
        const bf16x8 bv0 = ldfrag(&VT[cur][vrow][(lg ^ (vrow & 7)) * 8]);
        const bf16x8 bv1 = ldfrag(&VT[cur][vrow][((4 + lg) ^ (vrow & 7)) * 8]);
        o[dt] = __builtin_amdgcn_mfma_f32_16x16x32_bf16(ap0, bv0, o[dt], 0, 0, 0);
        o[dt] = __builtin_amdgcn_mfma_f32_16x16x32_bf16(ap1, bv1, o[dt], 0, 0, 0);
      }

      __syncthreads();   // tile[cur] reads done; next tile's DMA drained
      cur ^= 1;
    }
#undef STAGE_KV
  }

#pragma unroll
  for (int dt = 0; dt < 4; ++dt)
#pragma unroll
    for (int r = 0; r < 4; ++r)
      op[(size_t)(ibase + r) * D_N + dt * 16 + lr] = o[dt][r];
}

// ---------------------------------------------------------------------------
// Kernel 4: combine the NPART attn_out partials. out = sum_h opart[h].
// ---------------------------------------------------------------------------
__global__ __launch_bounds__(256) void combine(
    const float* __restrict__ opart, float* __restrict__ out) {
  const size_t idx = (size_t)blockIdx.x * 256 + threadIdx.x;
  const size_t stride = (size_t)B_N * S_N * D_N;
  out[idx] = opart[idx] + opart[stride + idx] + opart[2 * stride + idx] +
             opart[3 * stride + idx];
}

extern "C" void kernel_launch(void* const* d_in, const int* in_sizes, int n_in,
                              void* d_out, int out_size, void* d_ws, size_t ws_size,
                              hipStream_t stream) {
  (void)in_sizes; (void)n_in; (void)ws_size; (void)out_size;
  const float* x  = (const float*)d_in[0];
  const float* Wq = (const float*)d_in[1];
  const float* Wk = (const float*)d_in[2];
  const float* Wv = (const float*)d_in[3];
  float* out = (float*)d_out;

  __bf16* Qb = (__bf16*)d_ws;                         // [B*S][64] pre-scaled
  __bf16* Kb = Qb + (size_t)B_N * S_N * D_N;          // [B*S][64]
  __bf16* Vt = Kb + (size_t)B_N * S_N * D_N;          // [B][64][S] transposed
  float* zpart = (float*)(Vt + (size_t)B_N * S_N * D_N); // [NPART][B][S]
  float* opart = zpart + (size_t)NPART * B_N * S_N;      // [NPART][B][S][64]
  __bf16* Wt = (__bf16*)(opart + (size_t)NPART * B_N * S_N * D_N); // [3][64][384]

  w_prep<<<dim3(3 * 64 * C_N / 256), dim3(256), 0, stream>>>(Wq, Wk, Wv, Wt);
  qkv_mfma<<<dim3(B_N * S_N / 32), dim3(384), 0, stream>>>(x, Wt, Qb, Kb, Vt);
  col_stats<<<dim3(NPART * 32 * B_N), dim3(256), 0, stream>>>(Qb, Kb, zpart);
  attn_out<<<dim3(NPART * 32 * B_N), dim3(256), 0, stream>>>(Qb, Kb, Vt, zpart, opart);
  combine<<<dim3(B_N * S_N * D_N / 256), dim3(256), 0, stream>>>(opart, out);
}